// Round 9
// baseline (1422.992 us; speedup 1.0000x reference)
//
#include <hip/hip_runtime.h>
#include <hip/hip_bf16.h>
#include <math.h>

#define BB 16
#define TT 128
#define VV 137
#define CCH 3
#define TV (TT*VV)        // 17536 (real spatial size, for the mean divisor)
#define VP 160            // padded V
#define NP (TT*VP)        // 20480 padded spatial size
#define NCLS 226
#define APITCH 27136      // shorts per (b,t) adjacency slab (53 x 1KB DMA windows)

typedef __attribute__((ext_vector_type(8))) short bf16x8;
typedef __attribute__((ext_vector_type(4))) float f32x4;

__device__ __forceinline__ unsigned short f2bf(float x) {
  __hip_bfloat16 h = __float2bfloat16(x);
  return *reinterpret_cast<unsigned short*>(&h);
}

// async 16B direct-to-LDS copy (used by gmm)
__device__ __forceinline__ void gld_lds16(const unsigned short* src, unsigned short* ldst) {
  __builtin_amdgcn_global_load_lds(
      (const __attribute__((address_space(1))) void*)src,
      (__attribute__((address_space(3))) void*)ldst, 16, 0, 0);
}

// ---------------- BN stats ----------------
__global__ void bn_stats_kernel(const float* __restrict__ X,
                                const float* __restrict__ gamma,
                                const float* __restrict__ beta,
                                float* __restrict__ scale,
                                float* __restrict__ shift) {
  const int ch = blockIdx.x;           // 0..410
  const int v = ch / CCH, c = ch % CCH;
  const int tid = threadIdx.x;
  float s = 0.f, q = 0.f;
  for (int idx = tid; idx < BB*TT; idx += 256) {
    float x = X[(idx*VV + v)*CCH + c];
    s += x; q += x*x;
  }
  #pragma unroll
  for (int off = 32; off > 0; off >>= 1) {
    s += __shfl_down(s, off, 64);
    q += __shfl_down(q, off, 64);
  }
  __shared__ float ls[4], lq[4];
  const int wid = tid >> 6, lane = tid & 63;
  if (lane == 0) { ls[wid] = s; lq[wid] = q; }
  __syncthreads();
  if (tid == 0) {
    float S = ls[0]+ls[1]+ls[2]+ls[3];
    float Q = lq[0]+lq[1]+lq[2]+lq[3];
    const float inv_n = 1.f / (BB*TT);
    float mean = S * inv_n;
    float var = Q * inv_n - mean*mean;
    float sc = gamma[ch] * rsqrtf(var + 1e-5f);
    scale[ch] = sc;
    shift[ch] = beta[ch] - mean * sc;
  }
}

// ---------------- BN apply + pad to [b][n'=t*160+v][3] bf16 ----------------
__global__ void bn_apply_kernel(const float* __restrict__ X,
                                const float* __restrict__ scale,
                                const float* __restrict__ shift,
                                unsigned short* __restrict__ xn) {
  const int o = blockIdx.x*256 + threadIdx.x;
  if (o >= BB*NP*CCH) return;
  const int c = o % CCH;
  const int np = (o / CCH) % NP;
  const int b = o / (CCH*NP);
  const int t = np / VP, v = np % VP;
  float val = 0.f;
  if (v < VV) {
    const int ch = v*CCH + c;
    val = X[((b*TT + t)*VV + v)*CCH + c] * scale[ch] + shift[ch];
  }
  xn[o] = f2bf(val);
}

// ---------------- weight transpose: w[oc][ic][9] fp32 -> wT[kk][oc][ic] bf16 ----------------
__global__ void wtrans_kernel(const float* __restrict__ w, unsigned short* __restrict__ wT,
                              int OC, int IC) {
  const int o = blockIdx.x*256 + threadIdx.x;
  if (o >= OC*IC*9) return;
  const int ic = o % IC;
  const int oc = (o / IC) % OC;
  const int kk = o / (IC*OC);
  wT[o] = f2bf(w[(oc*IC + ic)*9 + kk]);
}

// ---------------- conv0 weights: w0[64][3][9] -> w0T[64][32] ----------------
__global__ void w0trans_kernel(const float* __restrict__ w0, unsigned short* __restrict__ w0T) {
  const int o = blockIdx.x*256 + threadIdx.x;
  if (o >= 64*32) return;
  const int k = o % 32, oc = o / 32;
  const int kk = k / 3, ic = k % 3;
  w0T[o] = (k < 27) ? f2bf(w0[(oc*3 + ic)*9 + kk]) : (unsigned short)0;
}

__global__ void zero_kernel(float* __restrict__ p, int n) {
  const int i = blockIdx.x*256 + threadIdx.x;
  if (i < n) p[i] = 0.f;
}

// ---------------- adjacency precompute: A[b*T+t][w*168+v] bf16 (pitch APITCH) ----------------
__global__ __launch_bounds__(256)
void adj_kernel(const float* __restrict__ X, unsigned short* __restrict__ A) {
  __shared__ float Xs[3][144];
  const int b = blockIdx.x / TT, t = blockIdx.x % TT;
  const int tid = threadIdx.x;
  for (int i = tid; i < 3*VV; i += 256) {
    const int c = i / VV, v = i % VV;
    Xs[c][v] = X[((b*TT + t)*VV + v)*CCH + c];
  }
  __syncthreads();
  unsigned short* Ab = A + (size_t)blockIdx.x * APITCH;
  for (int e = tid; e < VP*168; e += 256) {
    const int w = e / 168, v = e % 168;
    unsigned short val = 0;
    if (w < VV && v < VV) {
      const float d0 = Xs[0][v]-Xs[0][w];
      const float d1 = Xs[1][v]-Xs[1][w];
      const float d2 = Xs[2][v]-Xs[2][w];
      val = f2bf(__expf(-2.f * sqrtf(d0*d0 + d1*d1 + d2*d2)));
    }
    Ab[e] = val;
  }
}

// ---------------- conv0: K=32 im2col gather, 128n x 64oc MFMA tile ----------------
__global__ __launch_bounds__(256)
void conv0_mfma(const unsigned short* __restrict__ xn,   // [gb][NP][3] bf16
                const unsigned short* __restrict__ w0T,  // [64][32] bf16
                const float* __restrict__ bias,
                unsigned short* __restrict__ outp) {     // [gb][64][NP] bf16
  __shared__ unsigned short im_s[128*40];
  __shared__ unsigned short w_s[64*40];
  const int tid = threadIdx.x;
  const int b = blockIdx.z;
  const int n0 = blockIdx.x * 128;
  const int wave = tid >> 6, lane = tid & 63, quad = lane >> 4, l15 = lane & 15;

  {
    const int row = tid >> 2, cg = tid & 3;
    *(uint4*)&w_s[row*40 + cg*8] = *(const uint4*)(w0T + row*32 + cg*8);
  }
  for (int e = tid; e < 128*32; e += 256) {
    const int row = e >> 5, k = e & 31;
    unsigned short val = 0;
    if (k < 27) {
      const int kk = k / 3, ic = k % 3;
      const int srcn = n0 + row + (kk - 4)*VP;
      if (srcn >= 0 && srcn < NP)
        val = xn[((size_t)b*NP + srcn)*3 + ic];
    }
    im_s[row*40 + k] = val;
  }
  __syncthreads();

  f32x4 acc[2][4];
  #pragma unroll
  for (int mi = 0; mi < 2; ++mi)
    #pragma unroll
    for (int ct = 0; ct < 4; ++ct) acc[mi][ct] = (f32x4){0.f,0.f,0.f,0.f};

  bf16x8 af[2], bfr[4];
  #pragma unroll
  for (int mi = 0; mi < 2; ++mi)
    af[mi] = *(const bf16x8*)&im_s[((wave*2 + mi)*16 + l15)*40 + quad*8];
  #pragma unroll
  for (int ct = 0; ct < 4; ++ct)
    bfr[ct] = *(const bf16x8*)&w_s[(ct*16 + l15)*40 + quad*8];
  #pragma unroll
  for (int mi = 0; mi < 2; ++mi)
    #pragma unroll
    for (int ct = 0; ct < 4; ++ct)
      acc[mi][ct] = __builtin_amdgcn_mfma_f32_16x16x32_bf16(af[mi], bfr[ct], acc[mi][ct], 0, 0, 0);

  #pragma unroll
  for (int mi = 0; mi < 2; ++mi) {
    const int nbase = n0 + (wave*2 + mi)*16 + quad*4;
    #pragma unroll
    for (int ct = 0; ct < 4; ++ct) {
      const int oc = ct*16 + l15;
      const float bv = bias[oc];
      ushort4 pk;
      unsigned short* pp = (unsigned short*)&pk;
      #pragma unroll
      for (int r = 0; r < 4; ++r) {
        const int n = nbase + r;
        const int v = n - (n / VP) * VP;
        float x = acc[mi][ct][r] + bv;
        if (v >= VV) x = 0.f;
        pp[r] = f2bf(x);
      }
      *(ushort4*)(outp + ((size_t)b*64 + oc)*NP + nbase) = pk;
    }
  }
}

// ---------------- generic conv (K=9 temporal) as MFMA GEMM ----------------
// NO LDS, NO BARRIERS: both MFMA operands are 16B-contiguous per lane in
// global memory, so fragments load straight global->VGPR through L1/L2.
// A-frag: in[row = n0+mh+mt*16+l15 + shift][ics + (k0c+quad)*8]
// B-frag: wT[kk][oc = ocb0+chb+ct*16+l15][ics + (k0c+quad)*8]
#define KLOOP(GUARDED)                                                          \
  for (int kk = 0; kk < 9; ++kk) {                                              \
    const long shift = (long)(kk - 4) * VP;                                     \
    const unsigned short* wk = wB + (size_t)kk*OCtot*IC;                        \
    _Pragma("unroll")                                                           \
    for (int ici = 0; ici < NICS; ++ici) {                                      \
      _Pragma("unroll")                                                         \
      for (int k0c = 0; k0c < 8; k0c += 4) {                                    \
        const int ko = ici*64 + (k0c + quad)*8;                                 \
        bf16x8 af[NMT], bfr[NCT];                                               \
        _Pragma("unroll")                                                       \
        for (int mt = 0; mt < NMT; ++mt) {                                      \
          const long srcn = rowBase + mt*16 + shift;                            \
          const unsigned short* p;                                              \
          if (GUARDED) p = (srcn >= 0 && srcn < NP) ? inB + srcn*IC + ko : zsrc;\
          else         p = inB + srcn*IC + ko;                                  \
          af[mt] = *(const bf16x8*)p;                                           \
        }                                                                       \
        _Pragma("unroll")                                                       \
        for (int ct = 0; ct < NCT; ++ct)                                        \
          bfr[ct] = *(const bf16x8*)(wk + (size_t)ct*16*IC + ko);               \
        _Pragma("unroll")                                                       \
        for (int mt = 0; mt < NMT; ++mt)                                        \
          _Pragma("unroll")                                                     \
          for (int ct = 0; ct < NCT; ++ct)                                      \
            acc[mt][ct] = __builtin_amdgcn_mfma_f32_16x16x32_bf16(              \
                af[mt], bfr[ct], acc[mt][ct], 0, 0, 0);                         \
      }                                                                         \
    }                                                                           \
  }

template<int IC, int OCB, int NMT, int RELU, int FUSE>
__global__ __launch_bounds__(256)
void conv_mfma(const unsigned short* __restrict__ in,    // [gb][NP][IC] bf16
               const unsigned short* __restrict__ wT,    // [9][OCtot][IC] bf16
               const float* __restrict__ bias,
               unsigned short* __restrict__ outp,        // [gb][OCtot][NP] bf16
               float* __restrict__ mout,
               const unsigned short* __restrict__ zbuf,
               int OCtot, int ntiles, int nocb) {
  constexpr int NCT = OCB / 32;            // col-tiles per wave
  constexpr int MROWS = NMT * 32;          // rows per block
  constexpr int NICS = IC / 64;            // ics chunks (1 or 2)
  const int tid = threadIdx.x;
  const int wave = tid >> 6, lane = tid & 63, quad = lane >> 4, l15 = lane & 15;

  // XCD-contiguous remap (grids divisible by 8)
  const int per = gridDim.x >> 3;
  const int lin = (blockIdx.x & 7) * per + (blockIdx.x >> 3);
  const int tile = lin % ntiles;
  const int ocby = (lin / ntiles) % nocb;
  const int b    = lin / (ntiles * nocb);
  const int ocb0 = ocby * OCB;
  const int n0 = tile * MROWS;
  const int mh = (wave >> 1) * (NMT*16);    // m (n-row) half base
  const int chb = (wave & 1) * (OCB >> 1);  // col (oc) half base
  const bool interior = (n0 >= 640) && (n0 + MROWS + 640 <= NP);

  const long rowBase = (long)n0 + mh + l15;
  const unsigned short* inB = in + (size_t)b*NP*IC;
  const unsigned short* wB  = wT + (size_t)(ocb0 + chb + l15)*IC;
  const unsigned short* zsrc = zbuf + lane*8;

  f32x4 acc[NMT][NCT];
  #pragma unroll
  for (int mt = 0; mt < NMT; ++mt)
    #pragma unroll
    for (int ct = 0; ct < NCT; ++ct) acc[mt][ct] = (f32x4){0.f,0.f,0.f,0.f};

  if (interior) {
    KLOOP(0)
  } else {
    KLOOP(1)
  }

  if (!FUSE) {
    #pragma unroll
    for (int mt = 0; mt < NMT; ++mt) {
      const int nbase = n0 + mh + mt*16 + quad*4;
      #pragma unroll
      for (int ct = 0; ct < NCT; ++ct) {
        const int oc = ocb0 + chb + ct*16 + l15;
        const float bv = bias[oc];
        ushort4 pk;
        unsigned short* pp = (unsigned short*)&pk;
        #pragma unroll
        for (int r = 0; r < 4; ++r) {
          const int n = nbase + r;
          const int v = n - (n / VP) * VP;
          float x = acc[mt][ct][r] + bv;
          if (RELU) x = fmaxf(x, 0.f);
          if (v >= VV) x = 0.f;
          pp[r] = f2bf(x);
        }
        *(ushort4*)(outp + ((size_t)b*OCtot + oc)*NP + nbase) = pk;
      }
    }
  } else {
    #pragma unroll
    for (int ct = 0; ct < NCT; ++ct) {
      const int oc = ocb0 + chb + ct*16 + l15;
      const float bv = bias[oc];
      float s = 0.f;
      #pragma unroll
      for (int mt = 0; mt < NMT; ++mt) {
        const int nbase = n0 + mh + mt*16 + quad*4;
        #pragma unroll
        for (int r = 0; r < 4; ++r) {
          const int n = nbase + r;
          const int v = n - (n / VP) * VP;
          float x = acc[mt][ct][r] + bv;
          if (RELU) x = fmaxf(x, 0.f);
          if (v < VV) s += x;
        }
      }
      s += __shfl_down(s, 32, 64);
      s += __shfl_down(s, 16, 64);
      if (lane < 16) atomicAdd(&mout[(size_t)b*OCtot + oc], s * (1.f / TV));
    }
  }
}

// ---------------- graph matmul (MFMA), adjacency DMA'd from precomputed buffer ----------------
// act: [gb][Cin][NP] bf16 -> out: [gb][NP][Cin] bf16;  Cin = 64*MPW
template<int MPW>
__global__ __launch_bounds__(256)
void gmm_mfma(const unsigned short* __restrict__ A,   // [gb*T][APITCH] bf16
              const unsigned short* __restrict__ act,
              unsigned short* __restrict__ outp) {
  constexpr int Cin = 64 * MPW;
  __shared__ unsigned short As[APITCH];   // 54,272 B (valid region: 160x168)
  const int b = blockIdx.x / TT, t = blockIdx.x % TT;
  const int tid = threadIdx.x;
  const int wave = tid >> 6, lane = tid & 63, quad = lane >> 4, l15 = lane & 15;

  // DMA the adjacency slab: 53 x 1KB windows
  const unsigned short* Abt = A + (size_t)blockIdx.x * APITCH;
  for (int W = wave; W < 53; W += 4)
    gld_lds16(Abt + W*512 + lane*8, As + W*512);
  __syncthreads();

  f32x4 acc[MPW][10];
  #pragma unroll
  for (int mi = 0; mi < MPW; ++mi)
    #pragma unroll
    for (int ct = 0; ct < 10; ++ct) acc[mi][ct] = (f32x4){0.f,0.f,0.f,0.f};

  #pragma unroll
  for (int k0 = 0; k0 < VP; k0 += 32) {
    bf16x8 af[MPW];
    #pragma unroll
    for (int mi = 0; mi < MPW; ++mi) {
      const int c = (wave*MPW + mi)*16 + l15;
      af[mi] = *(const bf16x8*)(act + ((size_t)b*Cin + c)*NP + t*VP + k0 + quad*8);
    }
    #pragma unroll
    for (int ct = 0; ct < 10; ++ct) {
      const bf16x8 bfv = *(const bf16x8*)&As[(ct*16 + l15)*168 + k0 + quad*8];
      #pragma unroll
      for (int mi = 0; mi < MPW; ++mi)
        acc[mi][ct] = __builtin_amdgcn_mfma_f32_16x16x32_bf16(af[mi], bfv, acc[mi][ct], 0, 0, 0);
    }
  }

  #pragma unroll
  for (int mi = 0; mi < MPW; ++mi) {
    const int m0 = (wave*MPW + mi)*16;
    #pragma unroll
    for (int ct = 0; ct < 10; ++ct) {
      const int w = ct*16 + l15;
      const bool wok = (w < VV);
      ushort4 pk;
      unsigned short* pp = (unsigned short*)&pk;
      #pragma unroll
      for (int r = 0; r < 4; ++r)
        pp[r] = f2bf(wok ? acc[mi][ct][r] : 0.f);
      *(ushort4*)(outp + ((size_t)b*NP + t*VP + w)*Cin + m0 + quad*4) = pk;
    }
  }
}

// ---------------- FC ----------------
__global__ void fc_kernel(const float* __restrict__ mean,
                          const float* __restrict__ fcw,
                          const float* __restrict__ fcb,
                          float* __restrict__ out) {
  const int b = blockIdx.x;
  __shared__ float ms[256];
  const int tid = threadIdx.x;
  ms[tid] = mean[b*256 + tid];
  __syncthreads();
  if (tid < NCLS) {
    float acc = fcb[tid];
    for (int c = 0; c < 256; ++c) acc = fmaf(ms[c], fcw[tid*256 + c], acc);
    out[b*NCLS + tid] = acc;
  }
}

extern "C" void kernel_launch(void* const* d_in, const int* in_sizes, int n_in,
                              void* d_out, int out_size, void* d_ws, size_t ws_size,
                              hipStream_t stream) {
  const float* X    = (const float*)d_in[0];
  const float* bn_g = (const float*)d_in[1];
  const float* bn_b = (const float*)d_in[2];
  const float* w0   = (const float*)d_in[3];
  const float* cb0  = (const float*)d_in[4];
  const float* w1   = (const float*)d_in[5];
  const float* cb1  = (const float*)d_in[6];
  const float* w2   = (const float*)d_in[7];
  const float* cb2  = (const float*)d_in[8];
  const float* w3   = (const float*)d_in[9];
  const float* cb3  = (const float*)d_in[10];
  const float* fcw  = (const float*)d_in[11];
  const float* fcb  = (const float*)d_in[12];
  float* out = (float*)d_out;

  unsigned char* W = (unsigned char*)d_ws;
  size_t off = 0;
  auto alloc = [&](size_t bytes) -> void* {
    void* p = W + off;
    off += (bytes + 255) & ~(size_t)255;
    return p;
  };
  float* meanb  = (float*)alloc(BB*256*4);        // 16 KB
  float* zbuf_f = (float*)alloc(2048);            // 2 KB zero page
  float* scale  = (float*)alloc(512*4);
  float* shiftb = (float*)alloc(512*4);
  unsigned short* w0T = (unsigned short*)alloc(64*32*2);
  unsigned short* wT1 = (unsigned short*)alloc((size_t)9*64*64*2);
  unsigned short* wT2 = (unsigned short*)alloc((size_t)9*128*64*2);
  unsigned short* wT3 = (unsigned short*)alloc((size_t)9*256*128*2);
  unsigned short* xn  = (unsigned short*)alloc((size_t)BB*NP*3*2);
  const size_t fixedB = off;
  // per-batch: P + Q (bf16 128ch x NP) + adjacency slab (T x APITCH)
  const size_t perB = 2*((size_t)128*NP*2 + 256) + ((size_t)TT*APITCH*2 + 256);

  int g = 1;
  if (ws_size > fixedB + perB) {
    size_t gg = (ws_size - fixedB) / perB;
    g = (gg >= BB) ? BB : (int)gg;
  }
  unsigned short* P  = (unsigned short*)alloc((size_t)g*128*NP*2);
  unsigned short* Q  = (unsigned short*)alloc((size_t)g*128*NP*2);
  unsigned short* Ab = (unsigned short*)alloc((size_t)g*TT*APITCH*2);
  const unsigned short* zbuf = (const unsigned short*)zbuf_f;

  bn_stats_kernel<<<411, 256, 0, stream>>>(X, bn_g, bn_b, scale, shiftb);
  bn_apply_kernel<<<(BB*NP*3 + 255)/256, 256, 0, stream>>>(X, scale, shiftb, xn);
  w0trans_kernel<<<(64*32 + 255)/256, 256, 0, stream>>>(w0, w0T);
  wtrans_kernel<<<(9*64*64   + 255)/256, 256, 0, stream>>>(w1, wT1, 64, 64);
  wtrans_kernel<<<(9*128*64  + 255)/256, 256, 0, stream>>>(w2, wT2, 128, 64);
  wtrans_kernel<<<(9*256*128 + 255)/256, 256, 0, stream>>>(w3, wT3, 256, 128);
  zero_kernel<<<((BB*256 + 512) + 255)/256, 256, 0, stream>>>(meanb, BB*256 + 512);

  const int nt128 = NP / 128;  // 160 (conv0, conv2, conv3)
  const int nt256 = NP / 256;  // 80  (conv1)

  for (int b0 = 0; b0 < BB; b0 += g) {
    const int gb = (BB - b0 < g) ? (BB - b0) : g;
    const float* Xg = X + (size_t)b0 * TT * VV * CCH;
    const unsigned short* xng = xn + (size_t)b0 * NP * 3;
    float* mg = meanb + (size_t)b0 * 256;

    // adjacency once per group
    adj_kernel<<<gb*TT, 256, 0, stream>>>(Xg, Ab);
    // conv0: xn(3ch) -> P[64][NP]
    conv0_mfma<<<dim3(nt128,1,gb), 256, 0, stream>>>(xng, w0T, cb0, P);
    // layer 1
    gmm_mfma<1><<<gb*TT, 256, 0, stream>>>(Ab, P, Q);
    conv_mfma<64,64,8,1,0><<<nt256*gb, 256, 0, stream>>>(Q, wT1, cb1, P, nullptr, zbuf, 64, nt256, 1);
    // layer 2
    gmm_mfma<1><<<gb*TT, 256, 0, stream>>>(Ab, P, Q);
    conv_mfma<64,128,4,1,0><<<nt128*gb, 256, 0, stream>>>(Q, wT2, cb2, P, nullptr, zbuf, 128, nt128, 1);
    // layer 3: conv3 OCB=128 (2 oc-blocks), fused relu+mean
    gmm_mfma<2><<<gb*TT, 256, 0, stream>>>(Ab, P, Q);
    conv_mfma<128,128,4,1,1><<<nt128*2*gb, 256, 0, stream>>>(Q, wT3, cb3, nullptr, mg, zbuf, 256, nt128, 2);
  }

  fc_kernel<<<BB, 256, 0, stream>>>(meanb, fcw, fcb, out);
}

// Round 10
// 1151.259 us; speedup vs baseline: 1.2360x; 1.2360x over previous
//
#include <hip/hip_runtime.h>
#include <hip/hip_bf16.h>
#include <math.h>

#define BB 16
#define TT 128
#define VV 137
#define CCH 3
#define NN (VV*TT)        // 17536 spatial positions, v-major: n'' = v*128 + t
#define NCLS 226
#define APITCH 23040      // shorts per (b,t) adjacency slab: [144 rows][160 v]

typedef __attribute__((ext_vector_type(8))) short bf16x8;
typedef __attribute__((ext_vector_type(4))) float f32x4;

__device__ __forceinline__ unsigned short f2bf(float x) {
  __hip_bfloat16 h = __float2bfloat16(x);
  return *reinterpret_cast<unsigned short*>(&h);
}

// async 16B direct-to-LDS copy
__device__ __forceinline__ void gld_lds16(const unsigned short* src, unsigned short* ldst) {
  __builtin_amdgcn_global_load_lds(
      (const __attribute__((address_space(1))) void*)src,
      (__attribute__((address_space(3))) void*)ldst, 16, 0, 0);
}

// ---------------- BN stats ----------------
__global__ void bn_stats_kernel(const float* __restrict__ X,
                                const float* __restrict__ gamma,
                                const float* __restrict__ beta,
                                float* __restrict__ scale,
                                float* __restrict__ shift) {
  const int ch = blockIdx.x;           // 0..410
  const int v = ch / CCH, c = ch % CCH;
  const int tid = threadIdx.x;
  float s = 0.f, q = 0.f;
  for (int idx = tid; idx < BB*TT; idx += 256) {
    float x = X[(idx*VV + v)*CCH + c];
    s += x; q += x*x;
  }
  #pragma unroll
  for (int off = 32; off > 0; off >>= 1) {
    s += __shfl_down(s, off, 64);
    q += __shfl_down(q, off, 64);
  }
  __shared__ float ls[4], lq[4];
  const int wid = tid >> 6, lane = tid & 63;
  if (lane == 0) { ls[wid] = s; lq[wid] = q; }
  __syncthreads();
  if (tid == 0) {
    float S = ls[0]+ls[1]+ls[2]+ls[3];
    float Q = lq[0]+lq[1]+lq[2]+lq[3];
    const float inv_n = 1.f / (BB*TT);
    float mean = S * inv_n;
    float var = Q * inv_n - mean*mean;
    float sc = gamma[ch] * rsqrtf(var + 1e-5f);
    scale[ch] = sc;
    shift[ch] = beta[ch] - mean * sc;
  }
}

// ---------------- BN apply -> xn v-major [b][v*128+t][3] bf16 ----------------
__global__ void bn_apply_v(const float* __restrict__ X,
                           const float* __restrict__ scale,
                           const float* __restrict__ shift,
                           unsigned short* __restrict__ xn) {
  const int o = blockIdx.x*256 + threadIdx.x;
  if (o >= BB*NN*CCH) return;
  const int c = o % CCH;
  const int n = (o / CCH) % NN;
  const int b = o / (CCH*NN);
  const int v = n >> 7, t = n & 127;
  const int ch = v*CCH + c;
  float val = X[((b*TT + t)*VV + v)*CCH + c] * scale[ch] + shift[ch];
  xn[o] = f2bf(val);
}

// ---------------- weight transpose: w[oc][ic][9] fp32 -> wT[kk][oc][ic] bf16 ----------------
__global__ void wtrans_kernel(const float* __restrict__ w, unsigned short* __restrict__ wT,
                              int OC, int IC) {
  const int o = blockIdx.x*256 + threadIdx.x;
  if (o >= OC*IC*9) return;
  const int ic = o % IC;
  const int oc = (o / IC) % OC;
  const int kk = o / (IC*OC);
  wT[o] = f2bf(w[(oc*IC + ic)*9 + kk]);
}

// ---------------- conv0 weights: w0[64][3][9] -> w0T[64][32] ----------------
__global__ void w0trans_kernel(const float* __restrict__ w0, unsigned short* __restrict__ w0T) {
  const int o = blockIdx.x*256 + threadIdx.x;
  if (o >= 64*32) return;
  const int k = o % 32, oc = o / 32;
  const int kk = k / 3, ic = k % 3;
  w0T[o] = (k < 27) ? f2bf(w0[(oc*3 + ic)*9 + kk]) : (unsigned short)0;
}

__global__ void zero_kernel(float* __restrict__ p, int n) {
  const int i = blockIdx.x*256 + threadIdx.x;
  if (i < n) p[i] = 0.f;
}

// ---------------- adjacency precompute: slab [144][160] per (b,t), zero-padded ----------------
__global__ __launch_bounds__(256)
void adj_v(const float* __restrict__ X, unsigned short* __restrict__ A) {
  __shared__ float Xs[3][144];
  const int b = blockIdx.x / TT, t = blockIdx.x % TT;
  const int tid = threadIdx.x;
  for (int i = tid; i < 3*VV; i += 256) {
    const int c = i / VV, v = i % VV;
    Xs[c][v] = X[((b*TT + t)*VV + v)*CCH + c];
  }
  __syncthreads();
  unsigned short* Ab = A + (size_t)blockIdx.x * APITCH;
  for (int e = tid; e < 144*160; e += 256) {
    const int w = e / 160, v = e % 160;
    unsigned short val = 0;
    if (w < VV && v < VV) {
      const float d0 = Xs[0][v]-Xs[0][w];
      const float d1 = Xs[1][v]-Xs[1][w];
      const float d2 = Xs[2][v]-Xs[2][w];
      val = f2bf(__expf(-2.f * sqrtf(d0*d0 + d1*d1 + d2*d2)));
    }
    Ab[e] = val;
  }
}

// ---------------- conv0: v-major, block = one v-row (128 t), K=32 im2col ----------------
__global__ __launch_bounds__(256)
void conv0_v(const unsigned short* __restrict__ xn,   // [gb][NN][3]
             const unsigned short* __restrict__ w0T,  // [64][32]
             const float* __restrict__ bias,
             unsigned short* __restrict__ outp) {     // [gb][NN][64]
  __shared__ unsigned short im_s[128*40];
  __shared__ unsigned short w_s[64*40];
  __shared__ unsigned short ob[128*72];
  const int tid = threadIdx.x;
  const int v0 = blockIdx.x % 137;
  const int b  = blockIdx.x / 137;
  const int wave = tid >> 6, lane = tid & 63, quad = lane >> 4, l15 = lane & 15;
  const int mh = wave * 32;

  {
    const int row = tid >> 2, cg = tid & 3;
    *(uint4*)&w_s[row*40 + cg*8] = *(const uint4*)(w0T + row*32 + cg*8);
  }
  for (int e = tid; e < 128*32; e += 256) {
    const int t = e >> 5, k = e & 31;
    unsigned short val = 0;
    if (k < 27) {
      const int kk = k / 3, ic = k % 3;
      const int tp = t + kk - 4;
      if (tp >= 0 && tp < TT)
        val = xn[((size_t)b*NN + (size_t)v0*TT + tp)*3 + ic];
    }
    im_s[t*40 + k] = val;
  }
  __syncthreads();

  f32x4 acc[2][4];
  #pragma unroll
  for (int mt = 0; mt < 2; ++mt)
    #pragma unroll
    for (int ct = 0; ct < 4; ++ct) acc[mt][ct] = (f32x4){0.f,0.f,0.f,0.f};

  bf16x8 af[2], bfr[4];
  #pragma unroll
  for (int mt = 0; mt < 2; ++mt)
    af[mt] = *(const bf16x8*)&im_s[(mh + mt*16 + l15)*40 + quad*8];
  #pragma unroll
  for (int ct = 0; ct < 4; ++ct)
    bfr[ct] = *(const bf16x8*)&w_s[(ct*16 + l15)*40 + quad*8];
  #pragma unroll
  for (int mt = 0; mt < 2; ++mt)
    #pragma unroll
    for (int ct = 0; ct < 4; ++ct)
      acc[mt][ct] = __builtin_amdgcn_mfma_f32_16x16x32_bf16(af[mt], bfr[ct], acc[mt][ct], 0, 0, 0);

  // bounce: D[row=t][col=oc] -> ob[t][oc] -> coalesced slab write
  #pragma unroll
  for (int mt = 0; mt < 2; ++mt) {
    const int tb = mh + mt*16 + quad*4;
    #pragma unroll
    for (int ct = 0; ct < 4; ++ct) {
      const int oc = ct*16 + l15;
      const float bv = bias[oc];
      #pragma unroll
      for (int r = 0; r < 4; ++r)
        ob[(tb + r)*72 + oc] = f2bf(acc[mt][ct][r] + bv);
    }
  }
  __syncthreads();
  for (int rr = 0; rr < 4; ++rr) {
    const int idx = rr*256 + tid;
    const int t = idx >> 3, cg = idx & 7;
    uint4 val = *(const uint4*)&ob[t*72 + cg*8];
    *(uint4*)(outp + ((size_t)b*NN + (size_t)v0*TT + t)*64 + cg*8) = val;
  }
}

// ---------------- conv (K=9 over t), v-major: stage ONCE, weights direct from global ----
// in: [gb][NN][IC]; wT: [9][OCtot][IC]; out (non-FUSE): [gb][NN][OCB] (OCtot==OCB)
template<int IC, int OCB, int RELU, int FUSE>
__global__ __launch_bounds__(256)
void conv_v(const unsigned short* __restrict__ in,
            const unsigned short* __restrict__ wT,
            const float* __restrict__ bias,
            unsigned short* __restrict__ outp,
            float* __restrict__ mout,
            const unsigned short* __restrict__ zbuf,
            int OCtot, int nocb) {
  constexpr int NCT = OCB / 16;               // oc tiles per wave (4 or 8)
  constexpr int NWIN = 136*IC*2/1024;         // staging windows (17 or 34)
  constexpr int RPW  = 1024/(IC*2);           // rows per window (8 or 4)
  constexpr int OCP  = OCB + 8;               // bounce pitch
  __shared__ unsigned short in_s[136*IC];
  __shared__ unsigned short ob[FUSE ? 8 : 128*OCP];
  const int tid = threadIdx.x;
  const int wave = tid >> 6, lane = tid & 63, quad = lane >> 4, l15 = lane & 15;
  const int v0   = blockIdx.x % 137;
  const int ocby = (blockIdx.x / 137) % nocb;
  const int b    = blockIdx.x / (137*nocb);
  const int ocb0 = ocby * OCB;
  const int mh = wave * 32;

  // stage input window: rows r=0..135 <-> t' = r-4 (zero outside [0,128))
  {
    const int lr = (IC == 64) ? (lane >> 3) : (lane >> 4);
    const int ls = (IC == 64) ? (lane & 7)  : (lane & 15);
    #pragma unroll
    for (int wi = 0; wi < (NWIN+3)/4; ++wi) {
      const int W = wave + 4*wi;
      if (W < NWIN) {
        const int row = W*RPW + lr;
        const int sg = ls ^ (row & 7);
        const int tp = row - 4;
        const unsigned short* src = (tp >= 0 && tp < TT)
            ? in + ((size_t)b*NN + (size_t)v0*TT + tp)*IC + sg*8
            : zbuf + lane*8;
        gld_lds16(src, in_s + W*512);
      }
    }
  }
  __syncthreads();

  f32x4 acc[2][NCT];
  #pragma unroll
  for (int mt = 0; mt < 2; ++mt)
    #pragma unroll
    for (int ct = 0; ct < NCT; ++ct) acc[mt][ct] = (f32x4){0.f,0.f,0.f,0.f};

  for (int kk = 0; kk < 9; ++kk) {
    const unsigned short* wk = wT + ((size_t)kk*OCtot + ocb0 + l15)*IC;
    #pragma unroll
    for (int ks = 0; ks < IC/32; ++ks) {
      const int koff = ks*32 + quad*8;
      const int G = ks*4 + quad;
      bf16x8 af[2], bfr[NCT];
      #pragma unroll
      for (int mt = 0; mt < 2; ++mt) {
        const int row = mh + mt*16 + l15 + kk;
        af[mt] = *(const bf16x8*)&in_s[row*IC + ((G ^ (row & 7)) << 3)];
      }
      #pragma unroll
      for (int ct = 0; ct < NCT; ++ct)
        bfr[ct] = *(const bf16x8*)(wk + (size_t)ct*16*IC + koff);
      #pragma unroll
      for (int mt = 0; mt < 2; ++mt)
        #pragma unroll
        for (int ct = 0; ct < NCT; ++ct)
          acc[mt][ct] = __builtin_amdgcn_mfma_f32_16x16x32_bf16(af[mt], bfr[ct], acc[mt][ct], 0, 0, 0);
    }
  }

  if (FUSE) {
    // fused relu+mean: every (v,t) is real; divisor NN
    #pragma unroll
    for (int ct = 0; ct < NCT; ++ct) {
      const int oc = ocb0 + ct*16 + l15;
      const float bv = bias[oc];
      float s = 0.f;
      #pragma unroll
      for (int mt = 0; mt < 2; ++mt)
        #pragma unroll
        for (int r = 0; r < 4; ++r) {
          float x = acc[mt][ct][r] + bv;
          if (RELU) x = fmaxf(x, 0.f);
          s += x;
        }
      s += __shfl_down(s, 32, 64);
      s += __shfl_down(s, 16, 64);
      if (lane < 16) atomicAdd(&mout[(size_t)b*OCtot + oc], s * (1.f / NN));
    }
  } else {
    // bounce: D[row=t][col=oc] -> ob -> contiguous slab write
    #pragma unroll
    for (int mt = 0; mt < 2; ++mt) {
      const int tb = mh + mt*16 + quad*4;
      #pragma unroll
      for (int ct = 0; ct < NCT; ++ct) {
        const int oc = ct*16 + l15;
        const float bv = bias[oc];
        #pragma unroll
        for (int r = 0; r < 4; ++r) {
          float x = acc[mt][ct][r] + bv;
          if (RELU) x = fmaxf(x, 0.f);
          ob[(tb + r)*OCP + oc] = f2bf(x);
        }
      }
    }
    __syncthreads();
    constexpr int GPO = OCB / 8;     // out granules per row
    #pragma unroll
    for (int rr = 0; rr < 128*GPO/256; ++rr) {
      const int idx = rr*256 + tid;
      const int t = idx / GPO, cg = idx % GPO;
      uint4 val = *(const uint4*)&ob[t*OCP + cg*8];
      *(uint4*)(outp + ((size_t)b*NN + (size_t)v0*TT + t)*OCB + cg*8) = val;
    }
  }
}

// ---------------- graph matmul: LDS-transposed X^T, adjacency direct from global ----------------
// act/out: [gb][NN][Cfull] v-major channel-last; block = (b,t, c-half of 64)
__global__ __launch_bounds__(256)
void gmm_v(const unsigned short* __restrict__ A,     // [gb*T][APITCH]
           const unsigned short* __restrict__ act,
           unsigned short* __restrict__ outp,
           int Cfull) {
  __shared__ unsigned short xt[64*192];   // X^T[c][v swizzled], 24576 B
  __shared__ unsigned short ob[144*72];   // bounce D[w][c], 20736 B
  const int bt = blockIdx.x;
  const int b = bt / TT, t = bt % TT;
  const int ch = blockIdx.y;
  const int tid = threadIdx.x;
  const int wave = tid >> 6, lane = tid & 63, quad = lane >> 4, l15 = lane & 15;

  // transpose-stage: act[(v*128+t)][ch*64 + c] -> xt[c][v] (granule-swizzled), v<160 (0-pad 137+)
  {
    const int vl = tid >> 5;        // 8 v per round
    const int cp = tid & 31;        // uint column pair
    const int c0 = cp*2;
    for (int rr = 0; rr < 20; ++rr) {
      const int v = rr*8 + vl;
      unsigned int val = 0;
      if (v < VV)
        val = *(const unsigned int*)(act + ((size_t)b*NN + (size_t)v*TT + t)*Cfull + ch*64 + c0);
      const int vg = v >> 3, vr = v & 7;
      xt[c0*192 + (((vg ^ (c0 & 7)) << 3) | vr)]           = (unsigned short)(val & 0xffffu);
      xt[(c0+1)*192 + (((vg ^ ((c0+1) & 7)) << 3) | vr)]   = (unsigned short)(val >> 16);
    }
  }
  __syncthreads();

  const unsigned short* Abt = A + (size_t)bt * APITCH;
  f32x4 acc[9];
  #pragma unroll
  for (int ct = 0; ct < 9; ++ct) acc[ct] = (f32x4){0.f,0.f,0.f,0.f};

  const int m = wave*16 + l15;      // local c row
  #pragma unroll
  for (int ks = 0; ks < 5; ++ks) {
    const int G = ks*4 + quad;
    const bf16x8 af = *(const bf16x8*)&xt[m*192 + ((G ^ (m & 7)) << 3)];
    #pragma unroll
    for (int ct = 0; ct < 9; ++ct) {
      const bf16x8 bfv = *(const bf16x8*)(Abt + (ct*16 + l15)*160 + ks*32 + quad*8);
      acc[ct] = __builtin_amdgcn_mfma_f32_16x16x32_bf16(af, bfv, acc[ct], 0, 0, 0);
    }
  }

  // bounce: D[row=c][col=w] -> ob[w][c]
  #pragma unroll
  for (int ct = 0; ct < 9; ++ct) {
    const int w = ct*16 + l15;
    #pragma unroll
    for (int r = 0; r < 4; ++r) {
      const int c = wave*16 + quad*4 + r;
      ob[w*72 + c] = f2bf(acc[ct][r]);
    }
  }
  __syncthreads();
  {
    const int wl = tid >> 3, cg = tid & 7;
    #pragma unroll
    for (int rr = 0; rr < 5; ++rr) {
      const int w = rr*32 + wl;
      if (w < VV) {
        uint4 val = *(const uint4*)&ob[w*72 + cg*8];
        *(uint4*)(outp + ((size_t)b*NN + (size_t)w*TT + t)*Cfull + ch*64 + cg*8) = val;
      }
    }
  }
}

// ---------------- FC ----------------
__global__ void fc_kernel(const float* __restrict__ mean,
                          const float* __restrict__ fcw,
                          const float* __restrict__ fcb,
                          float* __restrict__ out) {
  const int b = blockIdx.x;
  __shared__ float ms[256];
  const int tid = threadIdx.x;
  ms[tid] = mean[b*256 + tid];
  __syncthreads();
  if (tid < NCLS) {
    float acc = fcb[tid];
    for (int c = 0; c < 256; ++c) acc = fmaf(ms[c], fcw[tid*256 + c], acc);
    out[b*NCLS + tid] = acc;
  }
}

extern "C" void kernel_launch(void* const* d_in, const int* in_sizes, int n_in,
                              void* d_out, int out_size, void* d_ws, size_t ws_size,
                              hipStream_t stream) {
  const float* X    = (const float*)d_in[0];
  const float* bn_g = (const float*)d_in[1];
  const float* bn_b = (const float*)d_in[2];
  const float* w0   = (const float*)d_in[3];
  const float* cb0  = (const float*)d_in[4];
  const float* w1   = (const float*)d_in[5];
  const float* cb1  = (const float*)d_in[6];
  const float* w2   = (const float*)d_in[7];
  const float* cb2  = (const float*)d_in[8];
  const float* w3   = (const float*)d_in[9];
  const float* cb3  = (const float*)d_in[10];
  const float* fcw  = (const float*)d_in[11];
  const float* fcb  = (const float*)d_in[12];
  float* out = (float*)d_out;

  unsigned char* W = (unsigned char*)d_ws;
  size_t off = 0;
  auto alloc = [&](size_t bytes) -> void* {
    void* p = W + off;
    off += (bytes + 255) & ~(size_t)255;
    return p;
  };
  float* meanb  = (float*)alloc(BB*256*4);        // 16 KB
  float* zbuf_f = (float*)alloc(2048);            // 2 KB zero page
  float* scale  = (float*)alloc(512*4);
  float* shiftb = (float*)alloc(512*4);
  unsigned short* w0T = (unsigned short*)alloc(64*32*2);
  unsigned short* wT1 = (unsigned short*)alloc((size_t)9*64*64*2);
  unsigned short* wT2 = (unsigned short*)alloc((size_t)9*128*64*2);
  unsigned short* wT3 = (unsigned short*)alloc((size_t)9*256*128*2);
  unsigned short* xn  = (unsigned short*)alloc((size_t)BB*NN*3*2);
  const size_t fixedB = off;
  // per-batch: P + Q (128ch x NN bf16) + adjacency slabs
  const size_t perB = 2*((size_t)NN*128*2 + 256) + ((size_t)TT*APITCH*2 + 256);

  int g = 1;
  if (ws_size > fixedB + perB) {
    size_t gg = (ws_size - fixedB) / perB;
    g = (gg >= BB) ? BB : (int)gg;
  }
  unsigned short* P  = (unsigned short*)alloc((size_t)g*NN*128*2);
  unsigned short* Q  = (unsigned short*)alloc((size_t)g*NN*128*2);
  unsigned short* Ab = (unsigned short*)alloc((size_t)g*TT*APITCH*2);
  const unsigned short* zbuf = (const unsigned short*)zbuf_f;

  bn_stats_kernel<<<411, 256, 0, stream>>>(X, bn_g, bn_b, scale, shiftb);
  bn_apply_v<<<(BB*NN*3 + 255)/256, 256, 0, stream>>>(X, scale, shiftb, xn);
  w0trans_kernel<<<(64*32 + 255)/256, 256, 0, stream>>>(w0, w0T);
  wtrans_kernel<<<(9*64*64   + 255)/256, 256, 0, stream>>>(w1, wT1, 64, 64);
  wtrans_kernel<<<(9*128*64  + 255)/256, 256, 0, stream>>>(w2, wT2, 128, 64);
  wtrans_kernel<<<(9*256*128 + 255)/256, 256, 0, stream>>>(w3, wT3, 256, 128);
  zero_kernel<<<((BB*256 + 512) + 255)/256, 256, 0, stream>>>(meanb, BB*256 + 512);

  for (int b0 = 0; b0 < BB; b0 += g) {
    const int gb = (BB - b0 < g) ? (BB - b0) : g;
    const float* Xg = X + (size_t)b0 * TT * VV * CCH;
    const unsigned short* xng = xn + (size_t)b0 * NN * 3;
    float* mg = meanb + (size_t)b0 * 256;

    adj_v<<<gb*TT, 256, 0, stream>>>(Xg, Ab);
    // conv0: xn(3ch) -> P [n''][64]
    conv0_v<<<137*gb, 256, 0, stream>>>(xng, w0T, cb0, P);
    // layer 1
    gmm_v<<<dim3(gb*TT, 1), 256, 0, stream>>>(Ab, P, Q, 64);
    conv_v<64,64,1,0><<<137*gb, 256, 0, stream>>>(Q, wT1, cb1, P, nullptr, zbuf, 64, 1);
    // layer 2
    gmm_v<<<dim3(gb*TT, 1), 256, 0, stream>>>(Ab, P, Q, 64);
    conv_v<64,128,1,0><<<137*gb, 256, 0, stream>>>(Q, wT2, cb2, P, nullptr, zbuf, 128, 1);
    // layer 3: gmm over 128ch (2 c-halves), conv3 fused relu+mean (2 oc-blocks)
    gmm_v<<<dim3(gb*TT, 2), 256, 0, stream>>>(Ab, P, Q, 128);
    conv_v<128,128,1,1><<<137*2*gb, 256, 0, stream>>>(Q, wT3, cb3, nullptr, mg, zbuf, 256, 2);
  }

  fc_kernel<<<BB, 256, 0, stream>>>(meanb, fcw, fcb, out);
}

// Round 11
// 612.108 us; speedup vs baseline: 2.3247x; 1.8808x over previous
//
#include <hip/hip_runtime.h>
#include <hip/hip_bf16.h>
#include <math.h>

#define BB 16
#define TT 128
#define VV 137
#define CCH 3
#define NN (VV*TT)        // 17536 spatial, v-major: n = v*128 + t
#define NCLS 226
#define APITCH 23040      // shorts per (b,t) adjacency slab: [144 w][160 v]

typedef __attribute__((ext_vector_type(8))) short bf16x8;
typedef __attribute__((ext_vector_type(4))) float f32x4;

__device__ __forceinline__ unsigned short f2bf(float x) {
  __hip_bfloat16 h = __float2bfloat16(x);
  return *reinterpret_cast<unsigned short*>(&h);
}

// async 16B direct-to-LDS copy
__device__ __forceinline__ void gld_lds16(const unsigned short* src, unsigned short* ldst) {
  __builtin_amdgcn_global_load_lds(
      (const __attribute__((address_space(1))) void*)src,
      (__attribute__((address_space(3))) void*)ldst, 16, 0, 0);
}

// ---------------- BN stats ----------------
__global__ void bn_stats_kernel(const float* __restrict__ X,
                                const float* __restrict__ gamma,
                                const float* __restrict__ beta,
                                float* __restrict__ scale,
                                float* __restrict__ shift) {
  const int ch = blockIdx.x;           // 0..410
  const int v = ch / CCH, c = ch % CCH;
  const int tid = threadIdx.x;
  float s = 0.f, q = 0.f;
  for (int idx = tid; idx < BB*TT; idx += 256) {
    float x = X[(idx*VV + v)*CCH + c];
    s += x; q += x*x;
  }
  #pragma unroll
  for (int off = 32; off > 0; off >>= 1) {
    s += __shfl_down(s, off, 64);
    q += __shfl_down(q, off, 64);
  }
  __shared__ float ls[4], lq[4];
  const int wid = tid >> 6, lane = tid & 63;
  if (lane == 0) { ls[wid] = s; lq[wid] = q; }
  __syncthreads();
  if (tid == 0) {
    float S = ls[0]+ls[1]+ls[2]+ls[3];
    float Q = lq[0]+lq[1]+lq[2]+lq[3];
    const float inv_n = 1.f / (BB*TT);
    float mean = S * inv_n;
    float var = Q * inv_n - mean*mean;
    float sc = gamma[ch] * rsqrtf(var + 1e-5f);
    scale[ch] = sc;
    shift[ch] = beta[ch] - mean * sc;
  }
}

// ---------------- BN apply -> xn v-major [b][v*128+t][3] bf16 ----------------
__global__ void bn_apply_v(const float* __restrict__ X,
                           const float* __restrict__ scale,
                           const float* __restrict__ shift,
                           unsigned short* __restrict__ xn) {
  const int o = blockIdx.x*256 + threadIdx.x;
  if (o >= BB*NN*CCH) return;
  const int c = o % CCH;
  const int n = (o / CCH) % NN;
  const int b = o / (CCH*NN);
  const int v = n >> 7, t = n & 127;
  const int ch = v*CCH + c;
  float val = X[((b*TT + t)*VV + v)*CCH + c] * scale[ch] + shift[ch];
  xn[o] = f2bf(val);
}

// ---------------- weight transpose: w[oc][ic][9] fp32 -> wT[kk][oc][ic] bf16 ----------------
__global__ void wtrans_kernel(const float* __restrict__ w, unsigned short* __restrict__ wT,
                              int OC, int IC) {
  const int o = blockIdx.x*256 + threadIdx.x;
  if (o >= OC*IC*9) return;
  const int ic = o % IC;
  const int oc = (o / IC) % OC;
  const int kk = o / (IC*OC);
  wT[o] = f2bf(w[(oc*IC + ic)*9 + kk]);
}

// ---------------- conv0 weights: w0[64][3][9] -> w0T[64][32] ----------------
__global__ void w0trans_kernel(const float* __restrict__ w0, unsigned short* __restrict__ w0T) {
  const int o = blockIdx.x*256 + threadIdx.x;
  if (o >= 64*32) return;
  const int k = o % 32, oc = o / 32;
  const int kk = k / 3, ic = k % 3;
  w0T[o] = (k < 27) ? f2bf(w0[(oc*3 + ic)*9 + kk]) : (unsigned short)0;
}

__global__ void zero_kernel(float* __restrict__ p, int n) {
  const int i = blockIdx.x*256 + threadIdx.x;
  if (i < n) p[i] = 0.f;
}

// ---------------- adjacency precompute: slab [144][160] per (b,t), zero-padded ----------------
__global__ __launch_bounds__(256)
void adj_v(const float* __restrict__ X, unsigned short* __restrict__ A) {
  __shared__ float Xs[3][144];
  const int b = blockIdx.x / TT, t = blockIdx.x % TT;
  const int tid = threadIdx.x;
  for (int i = tid; i < 3*VV; i += 256) {
    const int c = i / VV, v = i % VV;
    Xs[c][v] = X[((b*TT + t)*VV + v)*CCH + c];
  }
  __syncthreads();
  unsigned short* Ab = A + (size_t)blockIdx.x * APITCH;
  for (int e = tid; e < 144*160; e += 256) {
    const int w = e / 160, v = e % 160;
    unsigned short val = 0;
    if (w < VV && v < VV) {
      const float d0 = Xs[0][v]-Xs[0][w];
      const float d1 = Xs[1][v]-Xs[1][w];
      const float d2 = Xs[2][v]-Xs[2][w];
      val = f2bf(__expf(-2.f * sqrtf(d0*d0 + d1*d1 + d2*d2)));
    }
    Ab[e] = val;
  }
}

// ---------------- conv0: v-major, block = one v-row (128 t), K=32 im2col ----------------
__global__ __launch_bounds__(256)
void conv0_v(const unsigned short* __restrict__ xn,   // [gb][NN][3]
             const unsigned short* __restrict__ w0T,  // [64][32]
             const float* __restrict__ bias,
             unsigned short* __restrict__ outp) {     // [gb][NN][64]
  __shared__ unsigned short im_s[128*40];
  __shared__ unsigned short w_s[64*40];
  __shared__ unsigned short ob[128*72];
  const int tid = threadIdx.x;
  const int v0 = blockIdx.x % 137;
  const int b  = blockIdx.x / 137;
  const int wave = tid >> 6, lane = tid & 63, quad = lane >> 4, l15 = lane & 15;
  const int mh = wave * 32;

  {
    const int row = tid >> 2, cg = tid & 3;
    *(uint4*)&w_s[row*40 + cg*8] = *(const uint4*)(w0T + row*32 + cg*8);
  }
  for (int e = tid; e < 128*32; e += 256) {
    const int t = e >> 5, k = e & 31;
    unsigned short val = 0;
    if (k < 27) {
      const int kk = k / 3, ic = k % 3;
      const int tp = t + kk - 4;
      if (tp >= 0 && tp < TT)
        val = xn[((size_t)b*NN + (size_t)v0*TT + tp)*3 + ic];
    }
    im_s[t*40 + k] = val;
  }
  __syncthreads();

  f32x4 acc[2][4];
  #pragma unroll
  for (int mt = 0; mt < 2; ++mt)
    #pragma unroll
    for (int ct = 0; ct < 4; ++ct) acc[mt][ct] = (f32x4){0.f,0.f,0.f,0.f};

  bf16x8 af[2], bfr[4];
  #pragma unroll
  for (int mt = 0; mt < 2; ++mt)
    af[mt] = *(const bf16x8*)&im_s[(mh + mt*16 + l15)*40 + quad*8];
  #pragma unroll
  for (int ct = 0; ct < 4; ++ct)
    bfr[ct] = *(const bf16x8*)&w_s[(ct*16 + l15)*40 + quad*8];
  #pragma unroll
  for (int mt = 0; mt < 2; ++mt)
    #pragma unroll
    for (int ct = 0; ct < 4; ++ct)
      acc[mt][ct] = __builtin_amdgcn_mfma_f32_16x16x32_bf16(af[mt], bfr[ct], acc[mt][ct], 0, 0, 0);

  #pragma unroll
  for (int mt = 0; mt < 2; ++mt) {
    const int tb = mh + mt*16 + quad*4;
    #pragma unroll
    for (int ct = 0; ct < 4; ++ct) {
      const int oc = ct*16 + l15;
      const float bv = bias[oc];
      #pragma unroll
      for (int r = 0; r < 4; ++r)
        ob[(tb + r)*72 + oc] = f2bf(acc[mt][ct][r] + bv);
    }
  }
  __syncthreads();
  for (int rr = 0; rr < 4; ++rr) {
    const int idx = rr*256 + tid;
    const int t = idx >> 3, cg = idx & 7;
    uint4 val = *(const uint4*)&ob[t*72 + cg*8];
    *(uint4*)(outp + ((size_t)b*NN + (size_t)v0*TT + t)*64 + cg*8) = val;
  }
}

// ---------------- conv (K=9 over t), v-major ----------------
// block = 2 v-rows x OCB oc. Input staged ONCE; weights per-kk double-buffered in LDS.
// wave: NMT=4 m-tiles (64 t) x NCT col-tiles. 1 barrier per kk phase.
template<int IC, int OCB, int NCT, int RELU, int FUSE>
__global__ __launch_bounds__(256)
void conv_v2(const unsigned short* __restrict__ in,    // [gb][NN][IC]
             const unsigned short* __restrict__ wT,    // [9][OCtot][IC]
             const float* __restrict__ bias,
             unsigned short* __restrict__ outp,        // [gb][NN][OCB] (OCtot==OCB)
             float* __restrict__ mout,
             const unsigned short* __restrict__ zbuf,
             int OCtot, int nocb) {
  constexpr int NWIN = 136*IC/512;          // 1KB windows per v-row input
  constexpr int TWIN = 2*NWIN;
  constexpr int WWIN = OCB*IC/512;          // 1KB windows per weight slab
  constexpr int GPR  = IC/8;                // granules per row
  constexpr int RPW  = 512/IC;              // rows per 1KB window
  constexpr int INSZ = 2*136*IC;            // shorts
  constexpr int WSZ  = OCB*IC;              // shorts
  constexpr int OCP  = OCB + 8;
  constexpr int OBSZ = FUSE ? 0 : 256*OCP;
  constexpr int TOT  = (INSZ + 2*WSZ > OBSZ) ? (INSZ + 2*WSZ) : OBSZ;
  __shared__ unsigned short sh[TOT];
  unsigned short* in_s = sh;
  unsigned short* ob = sh;

  const int tid = threadIdx.x;
  const int wave = tid >> 6, lane = tid & 63, quad = lane >> 4, l15 = lane & 15;
  const int pair = blockIdx.x % 69;
  const int ocby = (blockIdx.x / 69) % nocb;
  const int b    = blockIdx.x / (69*nocb);
  const int v0 = pair*2;
  const int ocb0 = ocby * OCB;
  const int vr = wave >> 1;                 // wave's v-row (0/1)
  const int mhl = (wave & 1) * 64;          // wave's t-half base
  const bool vok = (v0 + vr) < VV;

  const int lrow = lane / GPR;
  const int lg   = lane % GPR;

  // ---- stage input: 2 v-row windows, once ----
  #pragma unroll
  for (int wi = 0; wi < (TWIN+3)/4; ++wi) {
    const int W = wave + 4*wi;
    if (W < TWIN) {
      const int vrW = W / NWIN;
      const int rl = (W % NWIN)*RPW + lrow;
      const int t = rl - 4;
      const int sg = lg ^ (rl & 7);
      const unsigned short* src = (t >= 0 && t < TT && (v0+vrW) < VV)
          ? in + ((size_t)b*NN + (size_t)(v0+vrW)*TT + t)*IC + (sg<<3)
          : zbuf + lane*8;
      gld_lds16(src, in_s + W*512);
    }
  }
  // ---- stage weights kk=0 into buf 0 ----
  auto stage_w = [&](int kk, int buf) {
    unsigned short* wb = sh + INSZ + buf*WSZ;
    #pragma unroll
    for (int wi = 0; wi < WWIN/4; ++wi) {
      const int W = wave + 4*wi;
      const int row = W*RPW + lrow;
      const int sg = lg ^ (row & 7);
      gld_lds16(wT + ((size_t)kk*OCtot + ocb0 + row)*IC + (sg<<3), wb + W*512);
    }
  };
  stage_w(0, 0);
  __syncthreads();

  f32x4 acc[4][NCT];
  #pragma unroll
  for (int mt = 0; mt < 4; ++mt)
    #pragma unroll
    for (int ct = 0; ct < NCT; ++ct) acc[mt][ct] = (f32x4){0.f,0.f,0.f,0.f};

  for (int kk = 0; kk < 9; ++kk) {
    if (kk < 8) stage_w(kk+1, (kk+1) & 1);
    const unsigned short* wb = sh + INSZ + (kk & 1)*WSZ;
    #pragma unroll
    for (int ks = 0; ks < IC/32; ++ks) {
      const int G = ks*4 + quad;
      bf16x8 af[4], bfr[NCT];
      #pragma unroll
      for (int mt = 0; mt < 4; ++mt) {
        const int row = mhl + mt*16 + l15 + kk;
        af[mt] = *(const bf16x8*)&in_s[vr*(136*IC) + row*IC + ((G ^ (row & 7)) << 3)];
      }
      #pragma unroll
      for (int ct = 0; ct < NCT; ++ct) {
        const int row = ct*16 + l15;
        bfr[ct] = *(const bf16x8*)&wb[row*IC + ((G ^ (row & 7)) << 3)];
      }
      #pragma unroll
      for (int mt = 0; mt < 4; ++mt)
        #pragma unroll
        for (int ct = 0; ct < NCT; ++ct)
          acc[mt][ct] = __builtin_amdgcn_mfma_f32_16x16x32_bf16(af[mt], bfr[ct], acc[mt][ct], 0, 0, 0);
    }
    __syncthreads();   // drains next-kk weight DMA; wbuf swap safe
  }

  if (FUSE) {
    if (vok) {
      #pragma unroll
      for (int ct = 0; ct < NCT; ++ct) {
        const int oc = ocb0 + ct*16 + l15;
        const float bv = bias[oc];
        float s = 0.f;
        #pragma unroll
        for (int mt = 0; mt < 4; ++mt)
          #pragma unroll
          for (int r = 0; r < 4; ++r) {
            float x = acc[mt][ct][r] + bv;
            if (RELU) x = fmaxf(x, 0.f);
            s += x;
          }
        s += __shfl_down(s, 32, 64);
        s += __shfl_down(s, 16, 64);
        if (lane < 16) atomicAdd(&mout[(size_t)b*OCtot + oc], s * (1.f / NN));
      }
    }
  } else {
    // acc -> ob (aliases in_s/w_s; all LDS reads done after last barrier)
    #pragma unroll
    for (int mt = 0; mt < 4; ++mt) {
      const int ro = vr*128 + mhl + mt*16 + quad*4;
      #pragma unroll
      for (int ct = 0; ct < NCT; ++ct) {
        const int oc = ct*16 + l15;
        const float bv = bias[oc];
        #pragma unroll
        for (int r = 0; r < 4; ++r) {
          float x = acc[mt][ct][r] + bv;
          if (RELU) x = fmaxf(x, 0.f);
          ob[(ro + r)*OCP + oc] = f2bf(x);
        }
      }
    }
    __syncthreads();
    constexpr int GPO = OCB/8;
    #pragma unroll
    for (int it = 0; it < 256*GPO/256; ++it) {
      const int task = it*256 + tid;
      const int ro = task / GPO, g = task % GPO;
      const int vrow = v0 + (ro >> 7);
      if (vrow < VV) {
        uint4 val = *(const uint4*)&ob[ro*OCP + g*8];
        *(uint4*)(outp + ((size_t)b*NN + (size_t)vrow*TT + (ro & 127))*OCB + g*8) = val;
      }
    }
  }
}

// ---------------- graph matmul: coalesced LDS transpose, adjacency direct from global ----
// act/out: [gb][NN][Cfull] v-major channel-last; block = (b,t) x c-half(64)
__global__ __launch_bounds__(256)
void gmm_v2(const unsigned short* __restrict__ A,     // [gb*T][APITCH]
            const unsigned short* __restrict__ act,
            unsigned short* __restrict__ outp,
            int Cfull) {
  __shared__ unsigned short xt[64*192];   // X^T[c][v granule-swizzled], 24.6 KB
  __shared__ unsigned short ob[144*72];   // bounce D[w][c], 20.7 KB
  const int bt = blockIdx.x;
  const int b = bt / TT, t = bt % TT;
  const int ch = blockIdx.y;
  const int tid = threadIdx.x;
  const int wave = tid >> 6, lane = tid & 63, quad = lane >> 4, l15 = lane & 15;

  // transpose-stage: task = v(0..159) x g(0..7); uint4 load (coalesced 128B per v-row),
  // scatter-write with double-XOR granule swizzle (conflict-free: g^(c&7)^(c>>3))
  #pragma unroll
  for (int it = 0; it < 5; ++it) {
    const int task = it*256 + tid;
    const int v = task >> 3, g = task & 7;
    uint4 val = {0u,0u,0u,0u};
    if (v < VV)
      val = *(const uint4*)(act + ((size_t)b*NN + (size_t)v*TT + t)*Cfull + ch*64 + g*8);
    const unsigned short* pv = (const unsigned short*)&val;
    const int vg = v >> 3, vrm = v & 7;
    #pragma unroll
    for (int j = 0; j < 8; ++j) {
      const int c = g*8 + j;
      const int slot = ((vg ^ (c & 7) ^ ((c >> 3) & 7)) << 3) | vrm;
      xt[c*192 + slot] = pv[j];
    }
  }
  __syncthreads();

  const unsigned short* Abt = A + (size_t)bt * APITCH;
  f32x4 acc[9];
  #pragma unroll
  for (int ct = 0; ct < 9; ++ct) acc[ct] = (f32x4){0.f,0.f,0.f,0.f};

  const int m = wave*16 + l15;      // local c row
  #pragma unroll
  for (int ks = 0; ks < 5; ++ks) {
    const int G = ks*4 + quad;
    const int slot = (G ^ (m & 7) ^ ((m >> 3) & 7)) << 3;
    const bf16x8 af = *(const bf16x8*)&xt[m*192 + slot];
    #pragma unroll
    for (int ct = 0; ct < 9; ++ct) {
      const bf16x8 bfv = *(const bf16x8*)(Abt + (ct*16 + l15)*160 + ks*32 + quad*8);
      acc[ct] = __builtin_amdgcn_mfma_f32_16x16x32_bf16(af, bfv, acc[ct], 0, 0, 0);
    }
  }

  // bounce: D[row=c][col=w] -> ob[w][c]
  #pragma unroll
  for (int ct = 0; ct < 9; ++ct) {
    const int w = ct*16 + l15;
    #pragma unroll
    for (int r = 0; r < 4; ++r) {
      const int c = wave*16 + quad*4 + r;
      ob[w*72 + c] = f2bf(acc[ct][r]);
    }
  }
  __syncthreads();
  {
    const int wl = tid >> 3, cg = tid & 7;
    #pragma unroll
    for (int rr = 0; rr < 5; ++rr) {
      const int w = rr*32 + wl;
      if (w < VV) {
        uint4 val = *(const uint4*)&ob[w*72 + cg*8];
        *(uint4*)(outp + ((size_t)b*NN + (size_t)w*TT + t)*Cfull + ch*64 + cg*8) = val;
      }
    }
  }
}

// ---------------- FC ----------------
__global__ void fc_kernel(const float* __restrict__ mean,
                          const float* __restrict__ fcw,
                          const float* __restrict__ fcb,
                          float* __restrict__ out) {
  const int b = blockIdx.x;
  __shared__ float ms[256];
  const int tid = threadIdx.x;
  ms[tid] = mean[b*256 + tid];
  __syncthreads();
  if (tid < NCLS) {
    float acc = fcb[tid];
    for (int c = 0; c < 256; ++c) acc = fmaf(ms[c], fcw[tid*256 + c], acc);
    out[b*NCLS + tid] = acc;
  }
}

extern "C" void kernel_launch(void* const* d_in, const int* in_sizes, int n_in,
                              void* d_out, int out_size, void* d_ws, size_t ws_size,
                              hipStream_t stream) {
  const float* X    = (const float*)d_in[0];
  const float* bn_g = (const float*)d_in[1];
  const float* bn_b = (const float*)d_in[2];
  const float* w0   = (const float*)d_in[3];
  const float* cb0  = (const float*)d_in[4];
  const float* w1   = (const float*)d_in[5];
  const float* cb1  = (const float*)d_in[6];
  const float* w2   = (const float*)d_in[7];
  const float* cb2  = (const float*)d_in[8];
  const float* w3   = (const float*)d_in[9];
  const float* cb3  = (const float*)d_in[10];
  const float* fcw  = (const float*)d_in[11];
  const float* fcb  = (const float*)d_in[12];
  float* out = (float*)d_out;

  unsigned char* W = (unsigned char*)d_ws;
  size_t off = 0;
  auto alloc = [&](size_t bytes) -> void* {
    void* p = W + off;
    off += (bytes + 255) & ~(size_t)255;
    return p;
  };
  float* meanb  = (float*)alloc(BB*256*4);        // 16 KB
  float* zbuf_f = (float*)alloc(2048);            // 2 KB zero page
  float* scale  = (float*)alloc(512*4);
  float* shiftb = (float*)alloc(512*4);
  unsigned short* w0T = (unsigned short*)alloc(64*32*2);
  unsigned short* wT1 = (unsigned short*)alloc((size_t)9*64*64*2);
  unsigned short* wT2 = (unsigned short*)alloc((size_t)9*128*64*2);
  unsigned short* wT3 = (unsigned short*)alloc((size_t)9*256*128*2);
  unsigned short* xn  = (unsigned short*)alloc((size_t)BB*NN*3*2);
  const size_t fixedB = off;
  const size_t perB = 2*((size_t)NN*128*2 + 256) + ((size_t)TT*APITCH*2 + 256);

  int g = 1;
  if (ws_size > fixedB + perB) {
    size_t gg = (ws_size - fixedB) / perB;
    g = (gg >= BB) ? BB : (int)gg;
  }
  unsigned short* P  = (unsigned short*)alloc((size_t)g*NN*128*2);
  unsigned short* Q  = (unsigned short*)alloc((size_t)g*NN*128*2);
  unsigned short* Ab = (unsigned short*)alloc((size_t)g*TT*APITCH*2);
  const unsigned short* zbuf = (const unsigned short*)zbuf_f;

  bn_stats_kernel<<<411, 256, 0, stream>>>(X, bn_g, bn_b, scale, shiftb);
  bn_apply_v<<<(BB*NN*3 + 255)/256, 256, 0, stream>>>(X, scale, shiftb, xn);
  w0trans_kernel<<<(64*32 + 255)/256, 256, 0, stream>>>(w0, w0T);
  wtrans_kernel<<<(9*64*64   + 255)/256, 256, 0, stream>>>(w1, wT1, 64, 64);
  wtrans_kernel<<<(9*128*64  + 255)/256, 256, 0, stream>>>(w2, wT2, 128, 64);
  wtrans_kernel<<<(9*256*128 + 255)/256, 256, 0, stream>>>(w3, wT3, 256, 128);
  zero_kernel<<<((BB*256 + 512) + 255)/256, 256, 0, stream>>>(meanb, BB*256 + 512);

  for (int b0 = 0; b0 < BB; b0 += g) {
    const int gb = (BB - b0 < g) ? (BB - b0) : g;
    const float* Xg = X + (size_t)b0 * TT * VV * CCH;
    const unsigned short* xng = xn + (size_t)b0 * NN * 3;
    float* mg = meanb + (size_t)b0 * 256;

    adj_v<<<gb*TT, 256, 0, stream>>>(Xg, Ab);
    // conv0: xn(3ch) -> P [n][64]
    conv0_v<<<137*gb, 256, 0, stream>>>(xng, w0T, cb0, P);
    // layer 1: gmm -> Q[n][64]; conv1 (IC64, OCB64, NCT4) -> P[n][64]
    gmm_v2<<<dim3(gb*TT, 1), 256, 0, stream>>>(Ab, P, Q, 64);
    conv_v2<64,64,4,1,0><<<69*gb, 256, 0, stream>>>(Q, wT1, cb1, P, nullptr, zbuf, 64, 1);
    // layer 2: gmm -> Q[n][64]; conv2 (IC64, OCB128, NCT8) -> P[n][128]
    gmm_v2<<<dim3(gb*TT, 1), 256, 0, stream>>>(Ab, P, Q, 64);
    conv_v2<64,128,8,1,0><<<69*gb, 256, 0, stream>>>(Q, wT2, cb2, P, nullptr, zbuf, 128, 1);
    // layer 3: gmm (128ch, 2 halves) -> Q[n][128]; conv3 (IC128, OCB128x2, FUSE)
    gmm_v2<<<dim3(gb*TT, 2), 256, 0, stream>>>(Ab, P, Q, 128);
    conv_v2<128,128,8,1,1><<<69*2*gb, 256, 0, stream>>>(Q, wT3, cb3, nullptr, mg, zbuf, 256, 2);
  }

  fc_kernel<<<BB, 256, 0, stream>>>(meanb, fcw, fcb, out);
}

// Round 12
// 547.242 us; speedup vs baseline: 2.6003x; 1.1185x over previous
//
#include <hip/hip_runtime.h>
#include <hip/hip_bf16.h>
#include <math.h>

#define BB 16
#define TT 128
#define VV 137
#define CCH 3
#define NN (VV*TT)        // 17536 spatial, v-major: n = v*128 + t
#define NCLS 226
#define APITCH 23040      // shorts per (b,t) adjacency slab: [144 w][160 v]

typedef __attribute__((ext_vector_type(8))) short bf16x8;
typedef __attribute__((ext_vector_type(4))) float f32x4;

__device__ __forceinline__ unsigned short f2bf(float x) {
  __hip_bfloat16 h = __float2bfloat16(x);
  return *reinterpret_cast<unsigned short*>(&h);
}

// async 16B direct-to-LDS copy
__device__ __forceinline__ void gld_lds16(const unsigned short* src, unsigned short* ldst) {
  __builtin_amdgcn_global_load_lds(
      (const __attribute__((address_space(1))) void*)src,
      (__attribute__((address_space(3))) void*)ldst, 16, 0, 0);
}

// ---------------- BN stats ----------------
__global__ void bn_stats_kernel(const float* __restrict__ X,
                                const float* __restrict__ gamma,
                                const float* __restrict__ beta,
                                float* __restrict__ scale,
                                float* __restrict__ shift) {
  const int ch = blockIdx.x;           // 0..410
  const int v = ch / CCH, c = ch % CCH;
  const int tid = threadIdx.x;
  float s = 0.f, q = 0.f;
  for (int idx = tid; idx < BB*TT; idx += 256) {
    float x = X[(idx*VV + v)*CCH + c];
    s += x; q += x*x;
  }
  #pragma unroll
  for (int off = 32; off > 0; off >>= 1) {
    s += __shfl_down(s, off, 64);
    q += __shfl_down(q, off, 64);
  }
  __shared__ float ls[4], lq[4];
  const int wid = tid >> 6, lane = tid & 63;
  if (lane == 0) { ls[wid] = s; lq[wid] = q; }
  __syncthreads();
  if (tid == 0) {
    float S = ls[0]+ls[1]+ls[2]+ls[3];
    float Q = lq[0]+lq[1]+lq[2]+lq[3];
    const float inv_n = 1.f / (BB*TT);
    float mean = S * inv_n;
    float var = Q * inv_n - mean*mean;
    float sc = gamma[ch] * rsqrtf(var + 1e-5f);
    scale[ch] = sc;
    shift[ch] = beta[ch] - mean * sc;
  }
}

// ---------------- BN apply -> xn v-major [b][v*128+t][3] bf16 ----------------
__global__ void bn_apply_v(const float* __restrict__ X,
                           const float* __restrict__ scale,
                           const float* __restrict__ shift,
                           unsigned short* __restrict__ xn) {
  const int o = blockIdx.x*256 + threadIdx.x;
  if (o >= BB*NN*CCH) return;
  const int c = o % CCH;
  const int n = (o / CCH) % NN;
  const int b = o / (CCH*NN);
  const int v = n >> 7, t = n & 127;
  const int ch = v*CCH + c;
  float val = X[((b*TT + t)*VV + v)*CCH + c] * scale[ch] + shift[ch];
  xn[o] = f2bf(val);
}

// ---------------- weight transpose: w[oc][ic][9] fp32 -> wT[kk][oc][ic] bf16 ----------------
__global__ void wtrans_kernel(const float* __restrict__ w, unsigned short* __restrict__ wT,
                              int OC, int IC) {
  const int o = blockIdx.x*256 + threadIdx.x;
  if (o >= OC*IC*9) return;
  const int ic = o % IC;
  const int oc = (o / IC) % OC;
  const int kk = o / (IC*OC);
  wT[o] = f2bf(w[(oc*IC + ic)*9 + kk]);
}

// ---------------- conv0 weights: w0[64][3][9] -> w0T[64][32] ----------------
__global__ void w0trans_kernel(const float* __restrict__ w0, unsigned short* __restrict__ w0T) {
  const int o = blockIdx.x*256 + threadIdx.x;
  if (o >= 64*32) return;
  const int k = o % 32, oc = o / 32;
  const int kk = k / 3, ic = k % 3;
  w0T[o] = (k < 27) ? f2bf(w0[(oc*3 + ic)*9 + kk]) : (unsigned short)0;
}

__global__ void zero_kernel(float* __restrict__ p, int n) {
  const int i = blockIdx.x*256 + threadIdx.x;
  if (i < n) p[i] = 0.f;
}

// ---------------- adjacency precompute: slab [144][160] per (b,t), zero-padded ----------------
__global__ __launch_bounds__(256)
void adj_v(const float* __restrict__ X, unsigned short* __restrict__ A) {
  __shared__ float Xs[3][144];
  const int b = blockIdx.x / TT, t = blockIdx.x % TT;
  const int tid = threadIdx.x;
  for (int i = tid; i < 3*VV; i += 256) {
    const int c = i / VV, v = i % VV;
    Xs[c][v] = X[((b*TT + t)*VV + v)*CCH + c];
  }
  __syncthreads();
  unsigned short* Ab = A + (size_t)blockIdx.x * APITCH;
  for (int e = tid; e < 144*160; e += 256) {
    const int w = e / 160, v = e % 160;
    unsigned short val = 0;
    if (w < VV && v < VV) {
      const float d0 = Xs[0][v]-Xs[0][w];
      const float d1 = Xs[1][v]-Xs[1][w];
      const float d2 = Xs[2][v]-Xs[2][w];
      val = f2bf(__expf(-2.f * sqrtf(d0*d0 + d1*d1 + d2*d2)));
    }
    Ab[e] = val;
  }
}

// ---------------- conv0: v-major, block = one v-row (128 t), K=32 im2col ----------------
__global__ __launch_bounds__(256)
void conv0_v(const unsigned short* __restrict__ xn,   // [gb][NN][3]
             const unsigned short* __restrict__ w0T,  // [64][32]
             const float* __restrict__ bias,
             unsigned short* __restrict__ outp) {     // [gb][NN][64]
  __shared__ unsigned short im_s[128*40];
  __shared__ unsigned short w_s[64*40];
  __shared__ unsigned short ob[128*72];
  const int tid = threadIdx.x;
  const int v0 = blockIdx.x % 137;
  const int b  = blockIdx.x / 137;
  const int wave = tid >> 6, lane = tid & 63, quad = lane >> 4, l15 = lane & 15;
  const int mh = wave * 32;

  {
    const int row = tid >> 2, cg = tid & 3;
    *(uint4*)&w_s[row*40 + cg*8] = *(const uint4*)(w0T + row*32 + cg*8);
  }
  for (int e = tid; e < 128*32; e += 256) {
    const int t = e >> 5, k = e & 31;
    unsigned short val = 0;
    if (k < 27) {
      const int kk = k / 3, ic = k % 3;
      const int tp = t + kk - 4;
      if (tp >= 0 && tp < TT)
        val = xn[((size_t)b*NN + (size_t)v0*TT + tp)*3 + ic];
    }
    im_s[t*40 + k] = val;
  }
  __syncthreads();

  f32x4 acc[2][4];
  #pragma unroll
  for (int mt = 0; mt < 2; ++mt)
    #pragma unroll
    for (int ct = 0; ct < 4; ++ct) acc[mt][ct] = (f32x4){0.f,0.f,0.f,0.f};

  bf16x8 af[2], bfr[4];
  #pragma unroll
  for (int mt = 0; mt < 2; ++mt)
    af[mt] = *(const bf16x8*)&im_s[(mh + mt*16 + l15)*40 + quad*8];
  #pragma unroll
  for (int ct = 0; ct < 4; ++ct)
    bfr[ct] = *(const bf16x8*)&w_s[(ct*16 + l15)*40 + quad*8];
  #pragma unroll
  for (int mt = 0; mt < 2; ++mt)
    #pragma unroll
    for (int ct = 0; ct < 4; ++ct)
      acc[mt][ct] = __builtin_amdgcn_mfma_f32_16x16x32_bf16(af[mt], bfr[ct], acc[mt][ct], 0, 0, 0);

  #pragma unroll
  for (int mt = 0; mt < 2; ++mt) {
    const int tb = mh + mt*16 + quad*4;
    #pragma unroll
    for (int ct = 0; ct < 4; ++ct) {
      const int oc = ct*16 + l15;
      const float bv = bias[oc];
      #pragma unroll
      for (int r = 0; r < 4; ++r)
        ob[(tb + r)*72 + oc] = f2bf(acc[mt][ct][r] + bv);
    }
  }
  __syncthreads();
  for (int rr = 0; rr < 4; ++rr) {
    const int idx = rr*256 + tid;
    const int t = idx >> 3, cg = idx & 7;
    uint4 val = *(const uint4*)&ob[t*72 + cg*8];
    *(uint4*)(outp + ((size_t)b*NN + (size_t)v0*TT + t)*64 + cg*8) = val;
  }
}

// ---------------- conv (K=9 over t), v-major, occupancy-tuned ----------------
// VROWS=2: block = 2 v-rows x OCB; wave = (v-row, t-half) x full OCB (NCT=OCB/16)
// VROWS=1: block = 1 v-row x OCB;  wave = t-half x oc-half       (NCT=OCB/32)
// WDBUF=1: weights double-buffered, 1 barrier/kk. WDBUF=0: single buffer, 2 barriers/kk.
template<int IC, int OCB, int VROWS, int WDBUF, int RELU, int FUSE>
__global__ __launch_bounds__(256)
void conv_v3(const unsigned short* __restrict__ in,    // [gb][NN][IC]
             const unsigned short* __restrict__ wT,    // [9][OCtot][IC]
             const float* __restrict__ bias,
             unsigned short* __restrict__ outp,        // [gb][NN][OCB] (OCtot==OCB)
             float* __restrict__ mout,
             const unsigned short* __restrict__ zbuf,
             int OCtot, int nocb) {
  constexpr int NCT  = (VROWS == 2) ? OCB/16 : OCB/32;
  constexpr int NWIN = 136*IC/512;          // 1KB windows per v-row input
  constexpr int TWIN = VROWS*NWIN;
  constexpr int WWIN = OCB*IC/512;          // 1KB windows per weight slab
  constexpr int GPR  = IC/8;                // granules per row
  constexpr int RPW  = 512/IC;              // rows per 1KB window
  constexpr int INSZ = VROWS*136*IC;        // shorts
  constexpr int WSZ  = OCB*IC;              // shorts
  constexpr int NWB  = WDBUF ? 2 : 1;
  constexpr int OCP  = OCB + 8;
  constexpr int OBSZ = FUSE ? 0 : VROWS*128*OCP;
  constexpr int TOT  = (INSZ + NWB*WSZ > OBSZ) ? (INSZ + NWB*WSZ) : OBSZ;
  __shared__ unsigned short sh[TOT];
  unsigned short* in_s = sh;
  unsigned short* ob = sh;

  const int tid = threadIdx.x;
  const int wave = tid >> 6, lane = tid & 63, quad = lane >> 4, l15 = lane & 15;
  const int nv = (VROWS == 2) ? 69 : 137;
  const int grp  = blockIdx.x % nv;
  const int ocby = (blockIdx.x / nv) % nocb;
  const int b    = blockIdx.x / (nv*nocb);
  const int v0 = grp * VROWS;
  const int ocb0 = ocby * OCB;
  const int vr  = (VROWS == 2) ? (wave >> 1) : 0;
  const int mhl = (VROWS == 2) ? ((wave & 1) * 64) : ((wave >> 1) * 64);
  const int chb = (VROWS == 2) ? 0 : ((wave & 1) * (OCB >> 1));
  const bool vok = (VROWS == 1) || ((v0 + vr) < VV);

  const int lrow = lane / GPR;
  const int lg   = lane % GPR;

  // ---- stage input once ----
  #pragma unroll
  for (int wi = 0; wi < (TWIN+3)/4; ++wi) {
    const int W = wave + 4*wi;
    if (W < TWIN) {
      const int vrW = W / NWIN;
      const int rl = (W % NWIN)*RPW + lrow;
      const int t = rl - 4;
      const int sg = lg ^ (rl & 7);
      const unsigned short* src = (t >= 0 && t < TT && (v0+vrW) < VV)
          ? in + ((size_t)b*NN + (size_t)(v0+vrW)*TT + t)*IC + (sg<<3)
          : zbuf + lane*8;
      gld_lds16(src, in_s + W*512);
    }
  }
  auto stage_w = [&](int kk, int buf) {
    unsigned short* wb = sh + INSZ + buf*WSZ;
    #pragma unroll
    for (int wi = 0; wi < WWIN/4; ++wi) {
      const int W = wave + 4*wi;
      const int row = W*RPW + lrow;
      const int sg = lg ^ (row & 7);
      gld_lds16(wT + ((size_t)kk*OCtot + ocb0 + row)*IC + (sg<<3), wb + W*512);
    }
  };

  f32x4 acc[4][NCT];
  #pragma unroll
  for (int mt = 0; mt < 4; ++mt)
    #pragma unroll
    for (int ct = 0; ct < NCT; ++ct) acc[mt][ct] = (f32x4){0.f,0.f,0.f,0.f};

  auto compute_kk = [&](int kk, int buf) {
    const unsigned short* wb = sh + INSZ + buf*WSZ;
    #pragma unroll
    for (int ks = 0; ks < IC/32; ++ks) {
      const int G = ks*4 + quad;
      bf16x8 af[4], bfr[NCT];
      #pragma unroll
      for (int mt = 0; mt < 4; ++mt) {
        const int row = mhl + mt*16 + l15 + kk;
        af[mt] = *(const bf16x8*)&in_s[vr*(136*IC) + row*IC + ((G ^ (row & 7)) << 3)];
      }
      #pragma unroll
      for (int ct = 0; ct < NCT; ++ct) {
        const int row = chb + ct*16 + l15;
        bfr[ct] = *(const bf16x8*)&wb[row*IC + ((G ^ (row & 7)) << 3)];
      }
      #pragma unroll
      for (int mt = 0; mt < 4; ++mt)
        #pragma unroll
        for (int ct = 0; ct < NCT; ++ct)
          acc[mt][ct] = __builtin_amdgcn_mfma_f32_16x16x32_bf16(af[mt], bfr[ct], acc[mt][ct], 0, 0, 0);
    }
  };

  if (WDBUF) {
    stage_w(0, 0);
    __syncthreads();
    for (int kk = 0; kk < 9; ++kk) {
      if (kk < 8) stage_w(kk+1, (kk+1) & 1);
      compute_kk(kk, kk & 1);
      __syncthreads();
    }
  } else {
    for (int kk = 0; kk < 9; ++kk) {
      stage_w(kk, 0);
      __syncthreads();      // drains weight DMA (and input DMA on kk=0)
      compute_kk(kk, 0);
      __syncthreads();      // readers done before next overwrite
    }
  }

  if (FUSE) {
    if (vok) {
      #pragma unroll
      for (int ct = 0; ct < NCT; ++ct) {
        const int oc = ocb0 + chb + ct*16 + l15;
        const float bv = bias[oc];
        float s = 0.f;
        #pragma unroll
        for (int mt = 0; mt < 4; ++mt)
          #pragma unroll
          for (int r = 0; r < 4; ++r) {
            float x = acc[mt][ct][r] + bv;
            if (RELU) x = fmaxf(x, 0.f);
            s += x;
          }
        s += __shfl_down(s, 32, 64);
        s += __shfl_down(s, 16, 64);
        if (lane < 16) atomicAdd(&mout[(size_t)b*OCtot + oc], s * (1.f / NN));
      }
    }
  } else {
    #pragma unroll
    for (int mt = 0; mt < 4; ++mt) {
      const int ro = vr*128 + mhl + mt*16 + quad*4;
      #pragma unroll
      for (int ct = 0; ct < NCT; ++ct) {
        const int oc = chb + ct*16 + l15;
        const float bv = bias[ocb0 + oc];
        #pragma unroll
        for (int r = 0; r < 4; ++r) {
          float x = acc[mt][ct][r] + bv;
          if (RELU) x = fmaxf(x, 0.f);
          ob[(ro + r)*OCP + oc] = f2bf(x);
        }
      }
    }
    __syncthreads();
    constexpr int GPO = OCB/8;
    #pragma unroll
    for (int it = 0; it < VROWS*128*GPO/256; ++it) {
      const int task = it*256 + tid;
      const int ro = task / GPO, g = task % GPO;
      const int vrow = v0 + (ro >> 7);
      if (vrow < VV) {
        uint4 val = *(const uint4*)&ob[ro*OCP + g*8];
        *(uint4*)(outp + ((size_t)b*NN + (size_t)vrow*TT + (ro & 127))*OCB + g*8) = val;
      }
    }
  }
}

// ---------------- graph matmul: coalesced LDS transpose, adjacency direct from global ----
__global__ __launch_bounds__(256)
void gmm_v2(const unsigned short* __restrict__ A,     // [gb*T][APITCH]
            const unsigned short* __restrict__ act,
            unsigned short* __restrict__ outp,
            int Cfull) {
  __shared__ unsigned short xt[64*192];
  __shared__ unsigned short ob[144*72];
  const int bt = blockIdx.x;
  const int b = bt / TT, t = bt % TT;
  const int ch = blockIdx.y;
  const int tid = threadIdx.x;
  const int wave = tid >> 6, lane = tid & 63, quad = lane >> 4, l15 = lane & 15;

  #pragma unroll
  for (int it = 0; it < 5; ++it) {
    const int task = it*256 + tid;
    const int v = task >> 3, g = task & 7;
    uint4 val = {0u,0u,0u,0u};
    if (v < VV)
      val = *(const uint4*)(act + ((size_t)b*NN + (size_t)v*TT + t)*Cfull + ch*64 + g*8);
    const unsigned short* pv = (const unsigned short*)&val;
    const int vg = v >> 3, vrm = v & 7;
    #pragma unroll
    for (int j = 0; j < 8; ++j) {
      const int c = g*8 + j;
      const int slot = ((vg ^ (c & 7) ^ ((c >> 3) & 7)) << 3) | vrm;
      xt[c*192 + slot] = pv[j];
    }
  }
  __syncthreads();

  const unsigned short* Abt = A + (size_t)bt * APITCH;
  f32x4 acc[9];
  #pragma unroll
  for (int ct = 0; ct < 9; ++ct) acc[ct] = (f32x4){0.f,0.f,0.f,0.f};

  const int m = wave*16 + l15;
  #pragma unroll
  for (int ks = 0; ks < 5; ++ks) {
    const int G = ks*4 + quad;
    const int slot = (G ^ (m & 7) ^ ((m >> 3) & 7)) << 3;
    const bf16x8 af = *(const bf16x8*)&xt[m*192 + slot];
    #pragma unroll
    for (int ct = 0; ct < 9; ++ct) {
      const bf16x8 bfv = *(const bf16x8*)(Abt + (ct*16 + l15)*160 + ks*32 + quad*8);
      acc[ct] = __builtin_amdgcn_mfma_f32_16x16x32_bf16(af, bfv, acc[ct], 0, 0, 0);
    }
  }

  #pragma unroll
  for (int ct = 0; ct < 9; ++ct) {
    const int w = ct*16 + l15;
    #pragma unroll
    for (int r = 0; r < 4; ++r) {
      const int c = wave*16 + quad*4 + r;
      ob[w*72 + c] = f2bf(acc[ct][r]);
    }
  }
  __syncthreads();
  {
    const int wl = tid >> 3, cg = tid & 7;
    #pragma unroll
    for (int rr = 0; rr < 5; ++rr) {
      const int w = rr*32 + wl;
      if (w < VV) {
        uint4 val = *(const uint4*)&ob[w*72 + cg*8];
        *(uint4*)(outp + ((size_t)b*NN + (size_t)w*TT + t)*Cfull + ch*64 + cg*8) = val;
      }
    }
  }
}

// ---------------- FC ----------------
__global__ void fc_kernel(const float* __restrict__ mean,
                          const float* __restrict__ fcw,
                          const float* __restrict__ fcb,
                          float* __restrict__ out) {
  const int b = blockIdx.x;
  __shared__ float ms[256];
  const int tid = threadIdx.x;
  ms[tid] = mean[b*256 + tid];
  __syncthreads();
  if (tid < NCLS) {
    float acc = fcb[tid];
    for (int c = 0; c < 256; ++c) acc = fmaf(ms[c], fcw[tid*256 + c], acc);
    out[b*NCLS + tid] = acc;
  }
}

extern "C" void kernel_launch(void* const* d_in, const int* in_sizes, int n_in,
                              void* d_out, int out_size, void* d_ws, size_t ws_size,
                              hipStream_t stream) {
  const float* X    = (const float*)d_in[0];
  const float* bn_g = (const float*)d_in[1];
  const float* bn_b = (const float*)d_in[2];
  const float* w0   = (const float*)d_in[3];
  const float* cb0  = (const float*)d_in[4];
  const float* w1   = (const float*)d_in[5];
  const float* cb1  = (const float*)d_in[6];
  const float* w2   = (const float*)d_in[7];
  const float* cb2  = (const float*)d_in[8];
  const float* w3   = (const float*)d_in[9];
  const float* cb3  = (const float*)d_in[10];
  const float* fcw  = (const float*)d_in[11];
  const float* fcb  = (const float*)d_in[12];
  float* out = (float*)d_out;

  unsigned char* W = (unsigned char*)d_ws;
  size_t off = 0;
  auto alloc = [&](size_t bytes) -> void* {
    void* p = W + off;
    off += (bytes + 255) & ~(size_t)255;
    return p;
  };
  float* meanb  = (float*)alloc(BB*256*4);        // 16 KB
  float* zbuf_f = (float*)alloc(2048);            // 2 KB zero page
  float* scale  = (float*)alloc(512*4);
  float* shiftb = (float*)alloc(512*4);
  unsigned short* w0T = (unsigned short*)alloc(64*32*2);
  unsigned short* wT1 = (unsigned short*)alloc((size_t)9*64*64*2);
  unsigned short* wT2 = (unsigned short*)alloc((size_t)9*128*64*2);
  unsigned short* wT3 = (unsigned short*)alloc((size_t)9*256*128*2);
  unsigned short* xn  = (unsigned short*)alloc((size_t)BB*NN*3*2);
  const size_t fixedB = off;
  const size_t perB = 2*((size_t)NN*128*2 + 256) + ((size_t)TT*APITCH*2 + 256);

  int g = 1;
  if (ws_size > fixedB + perB) {
    size_t gg = (ws_size - fixedB) / perB;
    g = (gg >= BB) ? BB : (int)gg;
  }
  unsigned short* P  = (unsigned short*)alloc((size_t)g*NN*128*2);
  unsigned short* Q  = (unsigned short*)alloc((size_t)g*NN*128*2);
  unsigned short* Ab = (unsigned short*)alloc((size_t)g*TT*APITCH*2);
  const unsigned short* zbuf = (const unsigned short*)zbuf_f;

  bn_stats_kernel<<<411, 256, 0, stream>>>(X, bn_g, bn_b, scale, shiftb);
  bn_apply_v<<<(BB*NN*3 + 255)/256, 256, 0, stream>>>(X, scale, shiftb, xn);
  w0trans_kernel<<<(64*32 + 255)/256, 256, 0, stream>>>(w0, w0T);
  wtrans_kernel<<<(9*64*64   + 255)/256, 256, 0, stream>>>(w1, wT1, 64, 64);
  wtrans_kernel<<<(9*128*64  + 255)/256, 256, 0, stream>>>(w2, wT2, 128, 64);
  wtrans_kernel<<<(9*256*128 + 255)/256, 256, 0, stream>>>(w3, wT3, 256, 128);
  zero_kernel<<<((BB*256 + 512) + 255)/256, 256, 0, stream>>>(meanb, BB*256 + 512);

  for (int b0 = 0; b0 < BB; b0 += g) {
    const int gb = (BB - b0 < g) ? (BB - b0) : g;
    const float* Xg = X + (size_t)b0 * TT * VV * CCH;
    const unsigned short* xng = xn + (size_t)b0 * NN * 3;
    float* mg = meanb + (size_t)b0 * 256;

    adj_v<<<gb*TT, 256, 0, stream>>>(Xg, Ab);
    // conv0: xn(3ch) -> P [n][64]
    conv0_v<<<137*gb, 256, 0, stream>>>(xng, w0T, cb0, P);
    // layer 1: gmm -> Q[n][64]; conv1 (2 v-rows, wdbuf) -> P[n][64]
    gmm_v2<<<dim3(gb*TT, 1), 256, 0, stream>>>(Ab, P, Q, 64);
    conv_v3<64,64,2,1,1,0><<<69*gb, 256, 0, stream>>>(Q, wT1, cb1, P, nullptr, zbuf, 64, 1);
    // layer 2: gmm -> Q[n][64]; conv2 (1 v-row, wdbuf, 3 blocks/CU) -> P[n][128]
    gmm_v2<<<dim3(gb*TT, 1), 256, 0, stream>>>(Ab, P, Q, 64);
    conv_v3<64,128,1,1,1,0><<<137*gb, 256, 0, stream>>>(Q, wT2, cb2, P, nullptr, zbuf, 128, 1);
    // layer 3: gmm (128ch, 2 halves) -> Q[n][128]; conv3 (1 v-row, single wbuf, 2 blocks/CU, FUSE)
    gmm_v2<<<dim3(gb*TT, 2), 256, 0, stream>>>(Ab, P, Q, 128);
    conv_v3<128,128,1,0,1,1><<<137*2*gb, 256, 0, stream>>>(Q, wT3, cb3, nullptr, mg, zbuf, 256, 2);
  }

  fc_kernel<<<BB, 256, 0, stream>>>(meanb, fcw, fcb, out);
}

// Round 13
// 528.383 us; speedup vs baseline: 2.6931x; 1.0357x over previous
//
#include <hip/hip_runtime.h>
#include <hip/hip_bf16.h>
#include <math.h>

#define BB 16
#define TT 128
#define VV 137
#define CCH 3
#define NN (VV*TT)        // 17536 spatial, v-major: n = v*128 + t
#define NCLS 226
#define APITCH 23040      // shorts per (b,t) adjacency slab: [144 w][160 v] = 45 x 1KB

typedef __attribute__((ext_vector_type(8))) short bf16x8;
typedef __attribute__((ext_vector_type(4))) float f32x4;

__device__ __forceinline__ unsigned short f2bf(float x) {
  __hip_bfloat16 h = __float2bfloat16(x);
  return *reinterpret_cast<unsigned short*>(&h);
}

// async 16B direct-to-LDS copy
__device__ __forceinline__ void gld_lds16(const unsigned short* src, unsigned short* ldst) {
  __builtin_amdgcn_global_load_lds(
      (const __attribute__((address_space(1))) void*)src,
      (__attribute__((address_space(3))) void*)ldst, 16, 0, 0);
}

// ---------------- BN stats ----------------
__global__ void bn_stats_kernel(const float* __restrict__ X,
                                const float* __restrict__ gamma,
                                const float* __restrict__ beta,
                                float* __restrict__ scale,
                                float* __restrict__ shift) {
  const int ch = blockIdx.x;           // 0..410
  const int v = ch / CCH, c = ch % CCH;
  const int tid = threadIdx.x;
  float s = 0.f, q = 0.f;
  for (int idx = tid; idx < BB*TT; idx += 256) {
    float x = X[(idx*VV + v)*CCH + c];
    s += x; q += x*x;
  }
  #pragma unroll
  for (int off = 32; off > 0; off >>= 1) {
    s += __shfl_down(s, off, 64);
    q += __shfl_down(q, off, 64);
  }
  __shared__ float ls[4], lq[4];
  const int wid = tid >> 6, lane = tid & 63;
  if (lane == 0) { ls[wid] = s; lq[wid] = q; }
  __syncthreads();
  if (tid == 0) {
    float S = ls[0]+ls[1]+ls[2]+ls[3];
    float Q = lq[0]+lq[1]+lq[2]+lq[3];
    const float inv_n = 1.f / (BB*TT);
    float mean = S * inv_n;
    float var = Q * inv_n - mean*mean;
    float sc = gamma[ch] * rsqrtf(var + 1e-5f);
    scale[ch] = sc;
    shift[ch] = beta[ch] - mean * sc;
  }
}

// ---------------- BN apply -> xn v-major [b][v*128+t][3] bf16 ----------------
__global__ void bn_apply_v(const float* __restrict__ X,
                           const float* __restrict__ scale,
                           const float* __restrict__ shift,
                           unsigned short* __restrict__ xn) {
  const int o = blockIdx.x*256 + threadIdx.x;
  if (o >= BB*NN*CCH) return;
  const int c = o % CCH;
  const int n = (o / CCH) % NN;
  const int b = o / (CCH*NN);
  const int v = n >> 7, t = n & 127;
  const int ch = v*CCH + c;
  float val = X[((b*TT + t)*VV + v)*CCH + c] * scale[ch] + shift[ch];
  xn[o] = f2bf(val);
}

// ---------------- weight transpose: w[oc][ic][9] fp32 -> wT[kk][oc][ic] bf16 ----------------
__global__ void wtrans_kernel(const float* __restrict__ w, unsigned short* __restrict__ wT,
                              int OC, int IC) {
  const int o = blockIdx.x*256 + threadIdx.x;
  if (o >= OC*IC*9) return;
  const int ic = o % IC;
  const int oc = (o / IC) % OC;
  const int kk = o / (IC*OC);
  wT[o] = f2bf(w[(oc*IC + ic)*9 + kk]);
}

// ---------------- conv0 weights: w0[64][3][9] -> w0T[64][32] ----------------
__global__ void w0trans_kernel(const float* __restrict__ w0, unsigned short* __restrict__ w0T) {
  const int o = blockIdx.x*256 + threadIdx.x;
  if (o >= 64*32) return;
  const int k = o % 32, oc = o / 32;
  const int kk = k / 3, ic = k % 3;
  w0T[o] = (k < 27) ? f2bf(w0[(oc*3 + ic)*9 + kk]) : (unsigned short)0;
}

__global__ void zero_kernel(float* __restrict__ p, int n) {
  const int i = blockIdx.x*256 + threadIdx.x;
  if (i < n) p[i] = 0.f;
}

// ---------------- adjacency precompute: slab [144][160] per (b,t), zero-padded ----------------
__global__ __launch_bounds__(256)
void adj_v(const float* __restrict__ X, unsigned short* __restrict__ A) {
  __shared__ float Xs[3][144];
  const int b = blockIdx.x / TT, t = blockIdx.x % TT;
  const int tid = threadIdx.x;
  for (int i = tid; i < 3*VV; i += 256) {
    const int c = i / VV, v = i % VV;
    Xs[c][v] = X[((b*TT + t)*VV + v)*CCH + c];
  }
  __syncthreads();
  unsigned short* Ab = A + (size_t)blockIdx.x * APITCH;
  for (int e = tid; e < 144*160; e += 256) {
    const int w = e / 160, v = e % 160;
    unsigned short val = 0;
    if (w < VV && v < VV) {
      const float d0 = Xs[0][v]-Xs[0][w];
      const float d1 = Xs[1][v]-Xs[1][w];
      const float d2 = Xs[2][v]-Xs[2][w];
      val = f2bf(__expf(-2.f * sqrtf(d0*d0 + d1*d1 + d2*d2)));
    }
    Ab[e] = val;
  }
}

// ---------------- conv0: v-major, block = one v-row (128 t), K=32 im2col ----------------
__global__ __launch_bounds__(256)
void conv0_v(const unsigned short* __restrict__ xn,   // [gb][NN][3]
             const unsigned short* __restrict__ w0T,  // [64][32]
             const float* __restrict__ bias,
             unsigned short* __restrict__ outp) {     // [gb][NN][64]
  __shared__ unsigned short im_s[128*40];
  __shared__ unsigned short w_s[64*40];
  __shared__ unsigned short ob[128*72];
  const int tid = threadIdx.x;
  const int v0 = blockIdx.x % 137;
  const int b  = blockIdx.x / 137;
  const int wave = tid >> 6, lane = tid & 63, quad = lane >> 4, l15 = lane & 15;
  const int mh = wave * 32;

  {
    const int row = tid >> 2, cg = tid & 3;
    *(uint4*)&w_s[row*40 + cg*8] = *(const uint4*)(w0T + row*32 + cg*8);
  }
  for (int e = tid; e < 128*32; e += 256) {
    const int t = e >> 5, k = e & 31;
    unsigned short val = 0;
    if (k < 27) {
      const int kk = k / 3, ic = k % 3;
      const int tp = t + kk - 4;
      if (tp >= 0 && tp < TT)
        val = xn[((size_t)b*NN + (size_t)v0*TT + tp)*3 + ic];
    }
    im_s[t*40 + k] = val;
  }
  __syncthreads();

  f32x4 acc[2][4];
  #pragma unroll
  for (int mt = 0; mt < 2; ++mt)
    #pragma unroll
    for (int ct = 0; ct < 4; ++ct) acc[mt][ct] = (f32x4){0.f,0.f,0.f,0.f};

  bf16x8 af[2], bfr[4];
  #pragma unroll
  for (int mt = 0; mt < 2; ++mt)
    af[mt] = *(const bf16x8*)&im_s[(mh + mt*16 + l15)*40 + quad*8];
  #pragma unroll
  for (int ct = 0; ct < 4; ++ct)
    bfr[ct] = *(const bf16x8*)&w_s[(ct*16 + l15)*40 + quad*8];
  #pragma unroll
  for (int mt = 0; mt < 2; ++mt)
    #pragma unroll
    for (int ct = 0; ct < 4; ++ct)
      acc[mt][ct] = __builtin_amdgcn_mfma_f32_16x16x32_bf16(af[mt], bfr[ct], acc[mt][ct], 0, 0, 0);

  #pragma unroll
  for (int mt = 0; mt < 2; ++mt) {
    const int tb = mh + mt*16 + quad*4;
    #pragma unroll
    for (int ct = 0; ct < 4; ++ct) {
      const int oc = ct*16 + l15;
      const float bv = bias[oc];
      #pragma unroll
      for (int r = 0; r < 4; ++r)
        ob[(tb + r)*72 + oc] = f2bf(acc[mt][ct][r] + bv);
    }
  }
  __syncthreads();
  for (int rr = 0; rr < 4; ++rr) {
    const int idx = rr*256 + tid;
    const int t = idx >> 3, cg = idx & 7;
    uint4 val = *(const uint4*)&ob[t*72 + cg*8];
    *(uint4*)(outp + ((size_t)b*NN + (size_t)v0*TT + t)*64 + cg*8) = val;
  }
}

// ---------------- conv (K=9 over t), v-major, occupancy-tuned ----------------
template<int IC, int OCB, int VROWS, int WDBUF, int RELU, int FUSE>
__global__ __launch_bounds__(256)
void conv_v3(const unsigned short* __restrict__ in,    // [gb][NN][IC]
             const unsigned short* __restrict__ wT,    // [9][OCtot][IC]
             const float* __restrict__ bias,
             unsigned short* __restrict__ outp,        // [gb][NN][OCB] (OCtot==OCB)
             float* __restrict__ mout,
             const unsigned short* __restrict__ zbuf,
             int OCtot, int nocb) {
  constexpr int NCT  = (VROWS == 2) ? OCB/16 : OCB/32;
  constexpr int NWIN = 136*IC/512;
  constexpr int TWIN = VROWS*NWIN;
  constexpr int WWIN = OCB*IC/512;
  constexpr int GPR  = IC/8;
  constexpr int RPW  = 512/IC;
  constexpr int INSZ = VROWS*136*IC;
  constexpr int WSZ  = OCB*IC;
  constexpr int NWB  = WDBUF ? 2 : 1;
  constexpr int OCP  = OCB + 8;
  constexpr int OBSZ = FUSE ? 0 : VROWS*128*OCP;
  constexpr int TOT  = (INSZ + NWB*WSZ > OBSZ) ? (INSZ + NWB*WSZ) : OBSZ;
  __shared__ unsigned short sh[TOT];
  unsigned short* in_s = sh;
  unsigned short* ob = sh;

  const int tid = threadIdx.x;
  const int wave = tid >> 6, lane = tid & 63, quad = lane >> 4, l15 = lane & 15;
  const int nv = (VROWS == 2) ? 69 : 137;
  const int grp  = blockIdx.x % nv;
  const int ocby = (blockIdx.x / nv) % nocb;
  const int b    = blockIdx.x / (nv*nocb);
  const int v0 = grp * VROWS;
  const int ocb0 = ocby * OCB;
  const int vr  = (VROWS == 2) ? (wave >> 1) : 0;
  const int mhl = (VROWS == 2) ? ((wave & 1) * 64) : ((wave >> 1) * 64);
  const int chb = (VROWS == 2) ? 0 : ((wave & 1) * (OCB >> 1));
  const bool vok = (VROWS == 1) || ((v0 + vr) < VV);

  const int lrow = lane / GPR;
  const int lg   = lane % GPR;

  // ---- stage input once ----
  #pragma unroll
  for (int wi = 0; wi < (TWIN+3)/4; ++wi) {
    const int W = wave + 4*wi;
    if (W < TWIN) {
      const int vrW = W / NWIN;
      const int rl = (W % NWIN)*RPW + lrow;
      const int t = rl - 4;
      const int sg = lg ^ (rl & 7);
      const unsigned short* src = (t >= 0 && t < TT && (v0+vrW) < VV)
          ? in + ((size_t)b*NN + (size_t)(v0+vrW)*TT + t)*IC + (sg<<3)
          : zbuf + lane*8;
      gld_lds16(src, in_s + W*512);
    }
  }
  auto stage_w = [&](int kk, int buf) {
    unsigned short* wb = sh + INSZ + buf*WSZ;
    #pragma unroll
    for (int wi = 0; wi < WWIN/4; ++wi) {
      const int W = wave + 4*wi;
      const int row = W*RPW + lrow;
      const int sg = lg ^ (row & 7);
      gld_lds16(wT + ((size_t)kk*OCtot + ocb0 + row)*IC + (sg<<3), wb + W*512);
    }
  };

  f32x4 acc[4][NCT];
  #pragma unroll
  for (int mt = 0; mt < 4; ++mt)
    #pragma unroll
    for (int ct = 0; ct < NCT; ++ct) acc[mt][ct] = (f32x4){0.f,0.f,0.f,0.f};

  auto compute_kk = [&](int kk, int buf) {
    const unsigned short* wb = sh + INSZ + buf*WSZ;
    #pragma unroll
    for (int ks = 0; ks < IC/32; ++ks) {
      const int G = ks*4 + quad;
      bf16x8 af[4], bfr[NCT];
      #pragma unroll
      for (int mt = 0; mt < 4; ++mt) {
        const int row = mhl + mt*16 + l15 + kk;
        af[mt] = *(const bf16x8*)&in_s[vr*(136*IC) + row*IC + ((G ^ (row & 7)) << 3)];
      }
      #pragma unroll
      for (int ct = 0; ct < NCT; ++ct) {
        const int row = chb + ct*16 + l15;
        bfr[ct] = *(const bf16x8*)&wb[row*IC + ((G ^ (row & 7)) << 3)];
      }
      #pragma unroll
      for (int mt = 0; mt < 4; ++mt)
        #pragma unroll
        for (int ct = 0; ct < NCT; ++ct)
          acc[mt][ct] = __builtin_amdgcn_mfma_f32_16x16x32_bf16(af[mt], bfr[ct], acc[mt][ct], 0, 0, 0);
    }
  };

  if (WDBUF) {
    stage_w(0, 0);
    __syncthreads();
    for (int kk = 0; kk < 9; ++kk) {
      if (kk < 8) stage_w(kk+1, (kk+1) & 1);
      compute_kk(kk, kk & 1);
      __syncthreads();
    }
  } else {
    for (int kk = 0; kk < 9; ++kk) {
      stage_w(kk, 0);
      __syncthreads();
      compute_kk(kk, 0);
      __syncthreads();
    }
  }

  if (FUSE) {
    if (vok) {
      #pragma unroll
      for (int ct = 0; ct < NCT; ++ct) {
        const int oc = ocb0 + chb + ct*16 + l15;
        const float bv = bias[oc];
        float s = 0.f;
        #pragma unroll
        for (int mt = 0; mt < 4; ++mt)
          #pragma unroll
          for (int r = 0; r < 4; ++r) {
            float x = acc[mt][ct][r] + bv;
            if (RELU) x = fmaxf(x, 0.f);
            s += x;
          }
        s += __shfl_down(s, 32, 64);
        s += __shfl_down(s, 16, 64);
        if (lane < 16) atomicAdd(&mout[(size_t)b*OCtot + oc], s * (1.f / NN));
      }
    }
  } else {
    #pragma unroll
    for (int mt = 0; mt < 4; ++mt) {
      const int ro = vr*128 + mhl + mt*16 + quad*4;
      #pragma unroll
      for (int ct = 0; ct < NCT; ++ct) {
        const int oc = chb + ct*16 + l15;
        const float bv = bias[ocb0 + oc];
        #pragma unroll
        for (int r = 0; r < 4; ++r) {
          float x = acc[mt][ct][r] + bv;
          if (RELU) x = fmaxf(x, 0.f);
          ob[(ro + r)*OCP + oc] = f2bf(x);
        }
      }
    }
    __syncthreads();
    constexpr int GPO = OCB/8;
    #pragma unroll
    for (int it = 0; it < VROWS*128*GPO/256; ++it) {
      const int task = it*256 + tid;
      const int ro = task / GPO, g = task % GPO;
      const int vrow = v0 + (ro >> 7);
      if (vrow < VV) {
        uint4 val = *(const uint4*)&ob[ro*OCP + g*8];
        *(uint4*)(outp + ((size_t)b*NN + (size_t)vrow*TT + (ro & 127))*OCB + g*8) = val;
      }
    }
  }
}

// ---------------- graph matmul v3: adjacency DMA'd into LDS, ob aliased over As ----------------
// act/out: [gb][NN][Cfull] v-major channel-last; block = (b,t) x c-half(64)
// LDS: xt 24.6 KB + As 46 KB = 70.7 KB -> 2 blocks/CU; ob (20.7 KB) aliases As after compute.
__global__ __launch_bounds__(256)
void gmm_v3(const unsigned short* __restrict__ A,     // [gb*T][APITCH]
            const unsigned short* __restrict__ act,
            unsigned short* __restrict__ outp,
            int Cfull) {
  __shared__ unsigned short sh[12288 + APITCH];
  unsigned short* xt = sh;            // X^T[c][v granule-swizzled], 64*192
  unsigned short* As = sh + 12288;    // [144 w][160 v]
  unsigned short* ob = sh + 12288;    // aliases As after compute barrier
  const int bt = blockIdx.x;
  const int b = bt / TT, t = bt % TT;
  const int ch = blockIdx.y;
  const int tid = threadIdx.x;
  const int wave = tid >> 6, lane = tid & 63, quad = lane >> 4, l15 = lane & 15;

  // DMA adjacency slab first (45 x 1KB windows) — latency hides under transpose below
  const unsigned short* Abt = A + (size_t)bt * APITCH;
  for (int W = wave; W < 45; W += 4)
    gld_lds16(Abt + W*512 + lane*8, As + W*512);

  // transpose-stage: uint4 load (coalesced 128B per v-row), double-XOR swizzled scatter
  #pragma unroll
  for (int it = 0; it < 5; ++it) {
    const int task = it*256 + tid;
    const int v = task >> 3, g = task & 7;
    uint4 val = {0u,0u,0u,0u};
    if (v < VV)
      val = *(const uint4*)(act + ((size_t)b*NN + (size_t)v*TT + t)*Cfull + ch*64 + g*8);
    const unsigned short* pv = (const unsigned short*)&val;
    const int vg = v >> 3, vrm = v & 7;
    #pragma unroll
    for (int j = 0; j < 8; ++j) {
      const int c = g*8 + j;
      const int slot = ((vg ^ (c & 7) ^ ((c >> 3) & 7)) << 3) | vrm;
      xt[c*192 + slot] = pv[j];
    }
  }
  __syncthreads();   // drains DMA + transpose

  f32x4 acc[9];
  #pragma unroll
  for (int ct = 0; ct < 9; ++ct) acc[ct] = (f32x4){0.f,0.f,0.f,0.f};

  const int m = wave*16 + l15;
  #pragma unroll
  for (int ks = 0; ks < 5; ++ks) {
    const int G = ks*4 + quad;
    const int slot = (G ^ (m & 7) ^ ((m >> 3) & 7)) << 3;
    const bf16x8 af = *(const bf16x8*)&xt[m*192 + slot];
    #pragma unroll
    for (int ct = 0; ct < 9; ++ct) {
      const bf16x8 bfv = *(const bf16x8*)&As[(ct*16 + l15)*160 + ks*32 + quad*8];
      acc[ct] = __builtin_amdgcn_mfma_f32_16x16x32_bf16(af, bfv, acc[ct], 0, 0, 0);
    }
  }
  __syncthreads();   // all As reads complete before ob overwrites it

  // bounce: D[row=c][col=w] -> ob[w][c]
  #pragma unroll
  for (int ct = 0; ct < 9; ++ct) {
    const int w = ct*16 + l15;
    #pragma unroll
    for (int r = 0; r < 4; ++r) {
      const int c = wave*16 + quad*4 + r;
      ob[w*72 + c] = f2bf(acc[ct][r]);
    }
  }
  __syncthreads();
  {
    const int wl = tid >> 3, cg = tid & 7;
    #pragma unroll
    for (int rr = 0; rr < 5; ++rr) {
      const int w = rr*32 + wl;
      if (w < VV) {
        uint4 val = *(const uint4*)&ob[w*72 + cg*8];
        *(uint4*)(outp + ((size_t)b*NN + (size_t)w*TT + t)*Cfull + ch*64 + cg*8) = val;
      }
    }
  }
}

// ---------------- FC ----------------
__global__ void fc_kernel(const float* __restrict__ mean,
                          const float* __restrict__ fcw,
                          const float* __restrict__ fcb,
                          float* __restrict__ out) {
  const int b = blockIdx.x;
  __shared__ float ms[256];
  const int tid = threadIdx.x;
  ms[tid] = mean[b*256 + tid];
  __syncthreads();
  if (tid < NCLS) {
    float acc = fcb[tid];
    for (int c = 0; c < 256; ++c) acc = fmaf(ms[c], fcw[tid*256 + c], acc);
    out[b*NCLS + tid] = acc;
  }
}

extern "C" void kernel_launch(void* const* d_in, const int* in_sizes, int n_in,
                              void* d_out, int out_size, void* d_ws, size_t ws_size,
                              hipStream_t stream) {
  const float* X    = (const float*)d_in[0];
  const float* bn_g = (const float*)d_in[1];
  const float* bn_b = (const float*)d_in[2];
  const float* w0   = (const float*)d_in[3];
  const float* cb0  = (const float*)d_in[4];
  const float* w1   = (const float*)d_in[5];
  const float* cb1  = (const float*)d_in[6];
  const float* w2   = (const float*)d_in[7];
  const float* cb2  = (const float*)d_in[8];
  const float* w3   = (const float*)d_in[9];
  const float* cb3  = (const float*)d_in[10];
  const float* fcw  = (const float*)d_in[11];
  const float* fcb  = (const float*)d_in[12];
  float* out = (float*)d_out;

  unsigned char* W = (unsigned char*)d_ws;
  size_t off = 0;
  auto alloc = [&](size_t bytes) -> void* {
    void* p = W + off;
    off += (bytes + 255) & ~(size_t)255;
    return p;
  };
  float* meanb  = (float*)alloc(BB*256*4);        // 16 KB
  float* zbuf_f = (float*)alloc(2048);            // 2 KB zero page
  float* scale  = (float*)alloc(512*4);
  float* shiftb = (float*)alloc(512*4);
  unsigned short* w0T = (unsigned short*)alloc(64*32*2);
  unsigned short* wT1 = (unsigned short*)alloc((size_t)9*64*64*2);
  unsigned short* wT2 = (unsigned short*)alloc((size_t)9*128*64*2);
  unsigned short* wT3 = (unsigned short*)alloc((size_t)9*256*128*2);
  unsigned short* xn  = (unsigned short*)alloc((size_t)BB*NN*3*2);
  const size_t fixedB = off;
  const size_t perB = 2*((size_t)NN*128*2 + 256) + ((size_t)TT*APITCH*2 + 256);

  int g = 1;
  if (ws_size > fixedB + perB) {
    size_t gg = (ws_size - fixedB) / perB;
    g = (gg >= BB) ? BB : (int)gg;
  }
  unsigned short* P  = (unsigned short*)alloc((size_t)g*NN*128*2);
  unsigned short* Q  = (unsigned short*)alloc((size_t)g*NN*128*2);
  unsigned short* Ab = (unsigned short*)alloc((size_t)g*TT*APITCH*2);
  const unsigned short* zbuf = (const unsigned short*)zbuf_f;

  bn_stats_kernel<<<411, 256, 0, stream>>>(X, bn_g, bn_b, scale, shiftb);
  bn_apply_v<<<(BB*NN*3 + 255)/256, 256, 0, stream>>>(X, scale, shiftb, xn);
  w0trans_kernel<<<(64*32 + 255)/256, 256, 0, stream>>>(w0, w0T);
  wtrans_kernel<<<(9*64*64   + 255)/256, 256, 0, stream>>>(w1, wT1, 64, 64);
  wtrans_kernel<<<(9*128*64  + 255)/256, 256, 0, stream>>>(w2, wT2, 128, 64);
  wtrans_kernel<<<(9*256*128 + 255)/256, 256, 0, stream>>>(w3, wT3, 256, 128);
  zero_kernel<<<((BB*256 + 512) + 255)/256, 256, 0, stream>>>(meanb, BB*256 + 512);

  for (int b0 = 0; b0 < BB; b0 += g) {
    const int gb = (BB - b0 < g) ? (BB - b0) : g;
    const float* Xg = X + (size_t)b0 * TT * VV * CCH;
    const unsigned short* xng = xn + (size_t)b0 * NN * 3;
    float* mg = meanb + (size_t)b0 * 256;

    adj_v<<<gb*TT, 256, 0, stream>>>(Xg, Ab);
    // conv0: xn(3ch) -> P [n][64]
    conv0_v<<<137*gb, 256, 0, stream>>>(xng, w0T, cb0, P);
    // layer 1: gmm -> Q[n][64]; conv1 (1 v-row, wdbuf, 4 blocks/CU) -> P[n][64]
    gmm_v3<<<dim3(gb*TT, 1), 256, 0, stream>>>(Ab, P, Q, 64);
    conv_v3<64,64,1,1,1,0><<<137*gb, 256, 0, stream>>>(Q, wT1, cb1, P, nullptr, zbuf, 64, 1);
    // layer 2: gmm -> Q[n][64]; conv2 (1 v-row, wdbuf, 3 blocks/CU) -> P[n][128]
    gmm_v3<<<dim3(gb*TT, 1), 256, 0, stream>>>(Ab, P, Q, 64);
    conv_v3<64,128,1,1,1,0><<<137*gb, 256, 0, stream>>>(Q, wT2, cb2, P, nullptr, zbuf, 128, 1);
    // layer 3: gmm (128ch, 2 halves) -> Q[n][128]; conv3 (1 v-row, single wbuf, FUSE)
    gmm_v3<<<dim3(gb*TT, 2), 256, 0, stream>>>(Ab, P, Q, 128);
    conv_v3<128,128,1,0,1,1><<<137*2*gb, 256, 0, stream>>>(Q, wT3, cb3, nullptr, mg, zbuf, 256, 2);
  }

  fc_kernel<<<BB, 256, 0, stream>>>(meanb, fcw, fcb, out);
}